// Round 1
// baseline (1901.336 us; speedup 1.0000x reference)
//
#include <hip/hip_runtime.h>

typedef _Float16 h8 __attribute__((ext_vector_type(8)));
typedef float f4 __attribute__((ext_vector_type(4)));

#define DEVINL __device__ __forceinline__

// ---------------------------------------------------------------------------
// Stage 1: per-level functional kernels.
// Each wave handles one (b, channel): computes fp16 copy of the row + the
// masked-sum functional vector V (padded), used both as flash-V and identity.
// ---------------------------------------------------------------------------

// c4: mean over 256 spatial. V4[b][i][16], p0 = mean, rest 0.
extern "C" __global__ __launch_bounds__(256)
void func_c4_kernel(const float* __restrict__ x, _Float16* __restrict__ xh,
                    float* __restrict__ V)
{
    int wave = threadIdx.x >> 6, lane = threadIdx.x & 63;
    int idx = blockIdx.x * 4 + wave;            // [0, 32768)
    int b = idx >> 11, i = idx & 2047;
    size_t base = (size_t)(b * 2048 + i) * 256;
    float acc = 0.f;
#pragma unroll
    for (int it = 0; it < 4; ++it) {
        float v = x[base + it * 64 + lane];
        xh[base + it * 64 + lane] = (_Float16)v;
        acc += v;
    }
#pragma unroll
    for (int m = 1; m < 64; m <<= 1) acc += __shfl_xor(acc, m);
    if (lane < 16)
        V[(size_t)(b * 2048 + i) * 16 + lane] = (lane == 0) ? acc * (1.f / 256.f) : 0.f;
}

// c3: 9 masked sums over 32x32 (3x3 stride-2 pad-1 conv tap classes).
// classes: kh=0 -> odd rows minus row31 ; kh=1 -> even rows ; kh=2 -> odd rows.
extern "C" __global__ __launch_bounds__(256)
void func_c3_kernel(const float* __restrict__ x, _Float16* __restrict__ xh,
                    float* __restrict__ V)
{
    __shared__ float scr[4][12];
    int wave = threadIdx.x >> 6, lane = threadIdx.x & 63;
    int idx = blockIdx.x * 4 + wave;            // [0, 16384)
    int b = idx >> 10, i = idx & 1023;
    size_t base = (size_t)(b * 1024 + i) * 1024;
    // lane -> col = lane&31, rowoff = lane>>5 ; iter it -> rows 2it, 2it+1
    float acc = 0.f;
    for (int it = 0; it < 15; ++it) {
        float v = x[base + it * 64 + lane];
        xh[base + it * 64 + lane] = (_Float16)v;
        acc += v;
    }
    float vl = x[base + 15 * 64 + lane];
    xh[base + 15 * 64 + lane] = (_Float16)vl;
    acc += vl;
    float tr = (lane >= 32) ? vl : 0.f;   // row-31 value (upper half lanes)
    float tcpre = acc;                    // lanes 31/63: column-31 parity sums
    float xpre = tr;                      // lane 63: x[31][31]
#pragma unroll
    for (int m = 2; m < 32; m <<= 1) {
        acc += __shfl_xor(acc, m);
        tr += __shfl_xor(tr, m);
    }
    if ((lane & 31) < 2) {
        int rp = lane >> 5, cp = lane & 1;
        scr[wave][rp * 2 + cp] = acc;          // G[rp][cp]
        if (rp == 1) scr[wave][4 + cp] = tr;   // T_r[cp] (row 31)
    }
    if ((lane & 31) == 31) {
        int rp = lane >> 5;
        scr[wave][6 + rp] = tcpre;             // T_c[rp] (col 31)
        if (rp == 1) scr[wave][8] = xpre;      // corner
    }
    __syncthreads();
    if (lane < 16) {
        float out = 0.f;
        if (lane < 9) {
            int kh = lane / 3, kw = lane - kh * 3;
            int rp = (kh == 1) ? 0 : 1, cp = (kw == 1) ? 0 : 1;
            bool er = (kh == 0), ec = (kw == 0);
            const float* s = scr[wave];
            out = s[rp * 2 + cp];
            if (er) out -= s[4 + cp];
            if (ec) out -= s[6 + rp];
            if (er && ec) out += s[8];
        }
        V[(size_t)(b * 1024 + i) * 16 + lane] = out;
    }
}

// c2: 81 masked sums over 64x64 (composition of two 3x3 s2 convs).
// Row classes: residue rm mod 4, possibly excluding row 61+(rm-1).
DEVINL float camU(const float* s, int p)
{
    int rc = p / 9, cc = p - rc * 9;
    int kh = rc / 3, kh2 = rc - kh * 3;
    int kw = cc / 3, kw2 = cc - kw * 3;
    int rm = (kh == 1) ? ((kh2 + 3) & 3) : (kh2 + 1);
    int cm = (kw == 1) ? ((kw2 + 3) & 3) : (kw2 + 1);
    bool er = (rc < 4), ec = (cc < 4);
    float u = s[rm * 4 + cm];
    if (er) u -= s[16 + (rm - 1) * 4 + cm];
    if (ec) u -= s[28 + rm * 3 + (cm - 1)];
    if (er && ec) u += s[40 + (rm - 1) * 3 + (cm - 1)];
    return u;
}

extern "C" __global__ __launch_bounds__(256)
void func_c2_kernel(const float* __restrict__ x, _Float16* __restrict__ xh,
                    float* __restrict__ V)
{
    __shared__ float scr[4][52];
    int wave = threadIdx.x >> 6, lane = threadIdx.x & 63;
    int idx = blockIdx.x * 4 + wave;            // [0, 8192)
    int b = idx >> 9, i = idx & 511;
    size_t base = (size_t)(b * 512 + i) * 4096;
    float acc[4] = {0.f, 0.f, 0.f, 0.f};        // per row-residue, this lane's col
    float tr[3];                                // rows 61..63 values
    for (int it = 0; it < 60; it += 4) {
#pragma unroll
        for (int rr = 0; rr < 4; ++rr) {
            float v = x[base + (size_t)(it + rr) * 64 + lane];
            xh[base + (size_t)(it + rr) * 64 + lane] = (_Float16)v;
            acc[rr] += v;
        }
    }
    {
        float v = x[base + 60 * 64 + lane];
        xh[base + 60 * 64 + lane] = (_Float16)v;
        acc[0] += v;
    }
#pragma unroll
    for (int rr = 1; rr < 4; ++rr) {
        float v = x[base + (size_t)(60 + rr) * 64 + lane];
        xh[base + (size_t)(60 + rr) * 64 + lane] = (_Float16)v;
        acc[rr] += v;
        tr[rr - 1] = v;
    }
    float tcx[4], xr[3];
#pragma unroll
    for (int g = 0; g < 4; ++g) tcx[g] = acc[g];   // lanes 61..63: T_c[rm]
#pragma unroll
    for (int g = 0; g < 3; ++g) xr[g] = tr[g];     // lanes 61..63: corners
#pragma unroll
    for (int m = 4; m < 64; m <<= 1) {
#pragma unroll
        for (int g = 0; g < 4; ++g) acc[g] += __shfl_xor(acc[g], m);
#pragma unroll
        for (int g = 0; g < 3; ++g) tr[g] += __shfl_xor(tr[g], m);
    }
    if (lane < 4) {
#pragma unroll
        for (int rm = 0; rm < 4; ++rm) scr[wave][rm * 4 + lane] = acc[rm];
#pragma unroll
        for (int rx = 0; rx < 3; ++rx) scr[wave][16 + rx * 4 + lane] = tr[rx];
    }
    if (lane >= 61) {
        int cx = lane - 61;
#pragma unroll
        for (int rm = 0; rm < 4; ++rm) scr[wave][28 + rm * 3 + cx] = tcx[rm];
#pragma unroll
        for (int rx = 0; rx < 3; ++rx) scr[wave][40 + rx * 3 + cx] = xr[rx];
    }
    __syncthreads();
    const float* s = scr[wave];
    size_t vbase = (size_t)(b * 512 + i) * 96;
    V[vbase + lane] = camU(s, lane);               // p = 0..63 (< 81)
    if (lane < 32) {
        int p = 64 + lane;
        V[vbase + p] = (p < 81) ? camU(s, p) : 0.f;
    }
}

// ---------------------------------------------------------------------------
// Stage 2: fused CAM flash kernel.  att = softmax_d(-xf xf^T), F = g*(att@V)+V
// Layouts (gfx950 mfma_f32_16x16x32_f16, verified mappings):
//   A/B frag: row/col = lane&15, k = (lane>>4)*8 + j   ;  C: col = lane&15,
//   row = (lane>>4)*4 + reg.
// ---------------------------------------------------------------------------
template <int N, int PPAD, int RT>
DEVINL void flash_impl(const _Float16* __restrict__ xf, const float* __restrict__ Vin,
                       float* __restrict__ Fout, const float* __restrict__ gptr,
                       int C, int r0, char* smem)
{
    const int tid = threadIdx.x;
    const int lane = tid & 63;
    const int wave = tid >> 6;
    const int l16 = lane & 15;
    const int quad = lane >> 4;
    const f4 fz = {0.f, 0.f, 0.f, 0.f};

    _Float16* B16 = (_Float16*)smem;            // [64][136]
    _Float16* W16 = B16 + 64 * 136;             // [4][16*RT][72] (carved max RT=2)
    _Float16* V16 = W16 + 4 * 32 * 72;          // [PPAD][72]
    _Float16* W16w = W16 + wave * (16 * RT * 72);

    f4 accp[RT][PPAD / 16];
    float m_run[RT][4], l_run[RT][4];
#pragma unroll
    for (int rt = 0; rt < RT; ++rt) {
#pragma unroll
        for (int ct = 0; ct < PPAD / 16; ++ct) accp[rt][ct] = fz;
#pragma unroll
        for (int g = 0; g < 4; ++g) { m_run[rt][g] = -3.0e38f; l_run[rt][g] = 0.f; }
    }

    const _Float16* Arow[RT];
#pragma unroll
    for (int rt = 0; rt < RT; ++rt)
        Arow[rt] = xf + (size_t)(r0 + wave * 16 * RT + rt * 16 + l16) * N + quad * 8;

    for (int d0 = 0; d0 < C; d0 += 64) {
        __syncthreads();  // previous tile's proj readers done before V16 overwrite
        for (int idx = tid; idx < 64 * PPAD; idx += 256) {
            int p = idx >> 6, d = idx & 63;
            V16[p * 72 + d] = (_Float16)Vin[(size_t)(d0 + d) * PPAD + p];
        }
        f4 e[RT][4];
#pragma unroll
        for (int rt = 0; rt < RT; ++rt)
#pragma unroll
            for (int t = 0; t < 4; ++t) e[rt][t] = fz;

        for (int k0 = 0; k0 < N; k0 += 128) {
            __syncthreads();
#pragma unroll
            for (int r = 0; r < 4; ++r) {
                int slot = tid + r * 256;       // 64 rows x 16 groups of 8 halves
                int d = slot >> 4;
                int k8 = (slot & 15) << 3;
                *(h8*)&B16[d * 136 + k8] = *(const h8*)&xf[(size_t)(d0 + d) * N + k0 + k8];
            }
            __syncthreads();
            h8 a[RT][4];
#pragma unroll
            for (int ks = 0; ks < 4; ++ks)
#pragma unroll
                for (int rt = 0; rt < RT; ++rt)
                    a[rt][ks] = *(const h8*)(Arow[rt] + k0 + ks * 32);
#pragma unroll
            for (int ks = 0; ks < 4; ++ks) {
#pragma unroll
                for (int t = 0; t < 4; ++t) {
                    h8 bf = *(const h8*)&B16[(l16 + 16 * t) * 136 + ks * 32 + quad * 8];
#pragma unroll
                    for (int rt = 0; rt < RT; ++rt)
                        e[rt][t] = __builtin_amdgcn_mfma_f32_16x16x32_f16(a[rt][ks], bf, e[rt][t], 0, 0, 0);
                }
            }
        }
        // online softmax over this 64-col tile; s = -energy
#pragma unroll
        for (int rt = 0; rt < RT; ++rt) {
            float mx[4], rs[4], al[4], mn[4];
#pragma unroll
            for (int g = 0; g < 4; ++g) {
                float v = -e[rt][0][g];
                v = fmaxf(v, -e[rt][1][g]);
                v = fmaxf(v, -e[rt][2][g]);
                v = fmaxf(v, -e[rt][3][g]);
                mx[g] = v;
            }
#pragma unroll
            for (int m = 1; m < 16; m <<= 1)
#pragma unroll
                for (int g = 0; g < 4; ++g) mx[g] = fmaxf(mx[g], __shfl_xor(mx[g], m));
#pragma unroll
            for (int g = 0; g < 4; ++g) {
                mn[g] = fmaxf(m_run[rt][g], mx[g]);
                al[g] = __expf(m_run[rt][g] - mn[g]);
                m_run[rt][g] = mn[g];
                rs[g] = 0.f;
            }
#pragma unroll
            for (int t = 0; t < 4; ++t)
#pragma unroll
                for (int g = 0; g < 4; ++g) {
                    float w = __expf(-e[rt][t][g] - mn[g]);
                    rs[g] += w;
                    W16w[(rt * 16 + quad * 4 + g) * 72 + l16 + 16 * t] = (_Float16)w;
                }
#pragma unroll
            for (int m = 1; m < 16; m <<= 1)
#pragma unroll
                for (int g = 0; g < 4; ++g) rs[g] += __shfl_xor(rs[g], m);
#pragma unroll
            for (int g = 0; g < 4; ++g) l_run[rt][g] = l_run[rt][g] * al[g] + rs[g];
#pragma unroll
            for (int ct = 0; ct < PPAD / 16; ++ct)
#pragma unroll
                for (int g = 0; g < 4; ++g) accp[rt][ct][g] *= al[g];
        }
        // projection mfma: acc += W @ V  (K = 64 tile cols; wave-private W16w)
#pragma unroll
        for (int kk = 0; kk < 64; kk += 32) {
            h8 wa[RT];
#pragma unroll
            for (int rt = 0; rt < RT; ++rt)
                wa[rt] = *(const h8*)&W16w[(rt * 16 + l16) * 72 + kk + quad * 8];
#pragma unroll
            for (int ct = 0; ct < PPAD / 16; ++ct) {
                h8 vb = *(const h8*)&V16[(ct * 16 + l16) * 72 + kk + quad * 8];
#pragma unroll
                for (int rt = 0; rt < RT; ++rt)
                    accp[rt][ct] = __builtin_amdgcn_mfma_f32_16x16x32_f16(wa[rt], vb, accp[rt][ct], 0, 0, 0);
            }
        }
    }
    float gamma = gptr[0];
#pragma unroll
    for (int rt = 0; rt < RT; ++rt)
#pragma unroll
        for (int ct = 0; ct < PPAD / 16; ++ct)
#pragma unroll
            for (int g = 0; g < 4; ++g) {
                int r = r0 + wave * 16 * RT + rt * 16 + quad * 4 + g;
                int p = ct * 16 + l16;
                size_t o = (size_t)r * PPAD + p;
                Fout[o] = gamma * (accp[rt][ct][g] / l_run[rt][g]) + Vin[o];
            }
}

extern "C" __global__ __launch_bounds__(256)
void flash_kernel(const _Float16* __restrict__ xf2, const _Float16* __restrict__ xf3,
                  const _Float16* __restrict__ xf4,
                  const float* __restrict__ V2, const float* __restrict__ V3,
                  const float* __restrict__ V4,
                  float* __restrict__ F2, float* __restrict__ F3, float* __restrict__ F4,
                  const float* __restrict__ g2, const float* __restrict__ g3,
                  const float* __restrict__ g4)
{
    extern __shared__ char smem[];
    int bid = blockIdx.x;
    if (bid < 128) {                         // c2: heaviest blocks first
        int b = bid >> 3, rb = bid & 7;
        flash_impl<4096, 96, 1>(xf2 + (size_t)b * 512 * 4096, V2 + (size_t)b * 512 * 96,
                                F2 + (size_t)b * 512 * 96, g2, 512, rb * 64, smem);
    } else if (bid < 256) {                  // c3
        int x = bid - 128;
        int b = x >> 3, rb = x & 7;
        flash_impl<1024, 16, 2>(xf3 + (size_t)b * 1024 * 1024, V3 + (size_t)b * 1024 * 16,
                                F3 + (size_t)b * 1024 * 16, g3, 1024, rb * 128, smem);
    } else {                                 // c4
        int x = bid - 256;
        int b = x >> 4, rb = x & 15;
        flash_impl<256, 16, 2>(xf4 + (size_t)b * 2048 * 256, V4 + (size_t)b * 2048 * 16,
                               F4 + (size_t)b * 2048 * 16, g4, 2048, rb * 128, smem);
    }
}

// ---------------------------------------------------------------------------
// Stage 3: tiny epilogue GEMMs on the functionals.
// ---------------------------------------------------------------------------

// V2m[b][j][kh*3+kw] = sum_i sum_{kh2,kw2} w2a[j,i,kh2,kw2]*F2[b,i,(kh*3+kh2)*9+kw*3+kw2]
extern "C" __global__ __launch_bounds__(256)
void ep_v2_kernel(const float* __restrict__ F2, const float* __restrict__ w2a,
                  float* __restrict__ V2m)
{
    int b = blockIdx.x >> 1;
    int j = (blockIdx.x & 1) * 256 + threadIdx.x;
    float acc[9];
#pragma unroll
    for (int k = 0; k < 9; ++k) acc[k] = 0.f;
    const float* Fb = F2 + (size_t)b * 512 * 96;
    const float* wj = w2a + (size_t)j * 512 * 9;
    for (int i = 0; i < 512; ++i) {
        const float* Fi = Fb + i * 96;       // block-uniform -> scalar loads
        const float* w = wj + i * 9;
#pragma unroll
        for (int kh2 = 0; kh2 < 3; ++kh2)
#pragma unroll
            for (int kw2 = 0; kw2 < 3; ++kw2) {
                float ww = w[kh2 * 3 + kw2];
#pragma unroll
                for (int kh = 0; kh < 3; ++kh)
#pragma unroll
                    for (int kw = 0; kw < 3; ++kw)
                        acc[kh * 3 + kw] += ww * Fi[(kh * 3 + kh2) * 9 + (kw * 3 + kw2)];
            }
    }
    float* o = V2m + ((size_t)b * 512 + j) * 9;
#pragma unroll
    for (int k = 0; k < 9; ++k) o[k] = acc[k];
}

// pooled-feature assembly: feat = [cam2, cam3, cam4, c4] pooled, [16][3584]
extern "C" __global__ __launch_bounds__(256)
void ep_pool_kernel(const float* __restrict__ V4, const float* __restrict__ F4,
                    const float* __restrict__ F3, const float* __restrict__ V2m,
                    const float* __restrict__ w4, const float* __restrict__ b4,
                    const float* __restrict__ w3, const float* __restrict__ w2b,
                    const float* __restrict__ b2b, float* __restrict__ PF)
{
    int bid = blockIdx.x, tid = threadIdx.x;
    if (bid < 96) {
        int br = bid / 32;
        int x = bid & 31;
        int b = x >> 1;
        int o = (x & 1) * 256 + tid;
        const float* wrow = w4 + (size_t)o * 2048;
        const float* V4b = V4 + (size_t)b * 2048 * 16;
        float pd4 = 0.f;
        for (int i = 0; i < 2048; ++i) pd4 += wrow[i] * V4b[(size_t)i * 16];
        pd4 += b4[o];                         // pooled(down4)
        if (br == 0) {                        // cam4 = pam4 + down4
            const float* F4b = F4 + (size_t)b * 2048 * 16;
            float s = 0.f;
            for (int i = 0; i < 2048; ++i) s += wrow[i] * F4b[(size_t)i * 16];
            PF[(size_t)b * 3584 + 1024 + o] = s + b4[o] + pd4;
        } else if (br == 1) {                 // cam3
            const float* F3b = F3 + (size_t)b * 1024 * 16;
            const float* w3r = w3 + (size_t)o * 1024 * 9;
            float s = 0.f;
            for (int i = 0; i < 1024; ++i) {
                const float* f = F3b + (size_t)i * 16;
                const float* w = w3r + (size_t)i * 9;
#pragma unroll
                for (int k = 0; k < 9; ++k) s += w[k] * f[k];
            }
            PF[(size_t)b * 3584 + 512 + o] = s * (1.f / 256.f) + pd4;
        } else {                              // cam2
            const float* Vb = V2m + (size_t)b * 512 * 9;
            const float* w2r = w2b + (size_t)o * 512 * 9;
            float s = 0.f;
            for (int j = 0; j < 512; ++j) {
#pragma unroll
                for (int k = 0; k < 9; ++k) s += w2r[j * 9 + k] * Vb[j * 9 + k];
            }
            PF[(size_t)b * 3584 + o] = s * (1.f / 256.f) + b2b[o] + pd4;
        }
    } else {                                  // raw c4 pooled means
        int idx = (bid - 96) * 256 + tid;     // [0, 32768)
        int b = idx >> 11, i = idx & 2047;
        PF[(size_t)b * 3584 + 1536 + i] = V4[((size_t)b * 2048 + i) * 16];
    }
}

extern "C" __global__ __launch_bounds__(256)
void ep_fc_kernel(const float* __restrict__ PF, const float* __restrict__ fcw,
                  const float* __restrict__ fcb, float* __restrict__ out)
{
    __shared__ float r0s[256], r1s[256];
    int b = blockIdx.x, tid = threadIdx.x;
    float p0 = 0.f, p1 = 0.f;
    for (int k = tid; k < 3584; k += 256) {
        float f = PF[(size_t)b * 3584 + k];
        p0 += fcw[k] * f;
        p1 += fcw[3584 + k] * f;
    }
    r0s[tid] = p0;
    r1s[tid] = p1;
    __syncthreads();
    for (int s = 128; s > 0; s >>= 1) {
        if (tid < s) { r0s[tid] += r0s[tid + s]; r1s[tid] += r1s[tid + s]; }
        __syncthreads();
    }
    if (tid == 0) {
        out[b * 2 + 0] = r0s[0] + fcb[0];
        out[b * 2 + 1] = r1s[0] + fcb[1];
    }
}

// ---------------------------------------------------------------------------

extern "C" void kernel_launch(void* const* d_in, const int* in_sizes, int n_in,
                              void* d_out, int out_size, void* d_ws, size_t ws_size,
                              hipStream_t stream)
{
    const float* c2 = (const float*)d_in[0];
    const float* c3 = (const float*)d_in[1];
    const float* c4 = (const float*)d_in[2];
    const float* w4 = (const float*)d_in[3];
    const float* b4 = (const float*)d_in[4];
    const float* w3 = (const float*)d_in[5];
    const float* w2a = (const float*)d_in[6];
    const float* w2b = (const float*)d_in[7];
    const float* b2b = (const float*)d_in[8];
    const float* g2 = (const float*)d_in[9];
    const float* g3 = (const float*)d_in[10];
    const float* g4 = (const float*)d_in[11];
    const float* fcw = (const float*)d_in[12];
    const float* fcb = (const float*)d_in[13];
    float* out = (float*)d_out;

    char* ws = (char*)d_ws;
    size_t off = 0;
    auto carve = [&](size_t bytes) -> char* {
        char* p = ws + off;
        off += (bytes + 255) & ~(size_t)255;
        return p;
    };
    _Float16* xf2 = (_Float16*)carve(16ull * 512 * 4096 * 2);
    _Float16* xf3 = (_Float16*)carve(16ull * 1024 * 1024 * 2);
    _Float16* xf4 = (_Float16*)carve(16ull * 2048 * 256 * 2);
    float* V2 = (float*)carve(16ull * 512 * 96 * 4);
    float* V3 = (float*)carve(16ull * 1024 * 16 * 4);
    float* V4 = (float*)carve(16ull * 2048 * 16 * 4);
    float* F2 = (float*)carve(16ull * 512 * 96 * 4);
    float* F3 = (float*)carve(16ull * 1024 * 16 * 4);
    float* F4 = (float*)carve(16ull * 2048 * 16 * 4);
    float* V2m = (float*)carve(16ull * 512 * 9 * 4);
    float* PF = (float*)carve(16ull * 3584 * 4);
    if (ws_size < off) return;  // workspace too small: fail visibly, no OOB

    func_c2_kernel<<<2048, 256, 0, stream>>>(c2, xf2, V2);
    func_c3_kernel<<<4096, 256, 0, stream>>>(c3, xf3, V3);
    func_c4_kernel<<<8192, 256, 0, stream>>>(c4, xf4, V4);
    // LDS: B16 64*136*2 + W16 4*32*72*2 + V16 96*72*2 = 49664 B
    flash_kernel<<<512, 256, 49664, stream>>>(xf2, xf3, xf4, V2, V3, V4,
                                              F2, F3, F4, g2, g3, g4);
    ep_v2_kernel<<<32, 256, 0, stream>>>(F2, w2a, V2m);
    ep_pool_kernel<<<224, 256, 0, stream>>>(V4, F4, F3, V2m, w4, b4, w3, w2b, b2b, PF);
    ep_fc_kernel<<<16, 256, 0, stream>>>(PF, fcw, fcb, out);
}

// Round 2
// 1552.529 us; speedup vs baseline: 1.2247x; 1.2247x over previous
//
#include <hip/hip_runtime.h>

typedef _Float16 h8 __attribute__((ext_vector_type(8)));
typedef float f4 __attribute__((ext_vector_type(4)));

#define DEVINL __device__ __forceinline__

// ---------------------------------------------------------------------------
// Blocked fp16 layout ("frag layout") for mfma_f32_16x16x32_f16:
//   element (row r, k) lives at frag_id = (r>>4)*(N>>5) + (k>>5),
//   lane = ((k>>3)&3)*16 + (r&15), offset = frag_id*512 + lane*8 + (k&7).
// A wave's A/B fragment load is then exactly  base + frag_id*512 + lane*8
// -> one coalesced global_load_dwordx4 per fragment. Same scheme for V
// (rows = p, k = d).
// ---------------------------------------------------------------------------

// ---------------------------------------------------------------------------
// Stage 1: functional kernels (V only; masked sums verified in round 1).
// ---------------------------------------------------------------------------

DEVINL void vtb_write(_Float16* vtb, int CB, int p, int d, float v)
{
    size_t off = (((size_t)(p >> 4) * CB) + (d >> 5)) * 512
               + (size_t)(((d >> 3) & 3) * 16 + (p & 15)) * 8 + (d & 7);
    vtb[off] = (_Float16)v;
}

// c4: mean over 256 spatial. Vtb4 p0 = mean, p1..15 = 0; V4d dense fp32 means.
extern "C" __global__ __launch_bounds__(256)
void func_c4_kernel(const float* __restrict__ x, _Float16* __restrict__ vtb,
                    float* __restrict__ V4d)
{
    int wave = threadIdx.x >> 6, lane = threadIdx.x & 63;
    int idx = blockIdx.x * 4 + wave;            // [0, 32768)
    int b = idx >> 11, i = idx & 2047;
    size_t base = (size_t)(b * 2048 + i) * 256;
    float acc = 0.f;
#pragma unroll
    for (int it = 0; it < 4; ++it) acc += x[base + it * 64 + lane];
#pragma unroll
    for (int m = 1; m < 64; m <<= 1) acc += __shfl_xor(acc, m);
    float mean = acc * (1.f / 256.f);
    _Float16* vb = vtb + (size_t)b * 16 * 2048;
    if (lane < 16) vtb_write(vb, 2048 >> 5, lane, i, (lane == 0) ? mean : 0.f);
    if (lane == 0) V4d[b * 2048 + i] = mean;
}

// c3: 9 masked sums over 32x32 (3x3 stride-2 pad-1 tap classes).
extern "C" __global__ __launch_bounds__(256)
void func_c3_kernel(const float* __restrict__ x, _Float16* __restrict__ vtb)
{
    __shared__ float scr[4][12];
    int wave = threadIdx.x >> 6, lane = threadIdx.x & 63;
    int idx = blockIdx.x * 4 + wave;            // [0, 16384)
    int b = idx >> 10, i = idx & 1023;
    size_t base = (size_t)(b * 1024 + i) * 1024;
    float acc = 0.f;
    for (int it = 0; it < 15; ++it) acc += x[base + it * 64 + lane];
    float vl = x[base + 15 * 64 + lane];
    acc += vl;
    float tr = (lane >= 32) ? vl : 0.f;   // row-31 value
    float tcpre = acc;                    // lanes 31/63: col-31 parity sums
    float xpre = tr;                      // lane 63: x[31][31]
#pragma unroll
    for (int m = 2; m < 32; m <<= 1) {
        acc += __shfl_xor(acc, m);
        tr += __shfl_xor(tr, m);
    }
    if ((lane & 31) < 2) {
        int rp = lane >> 5, cp = lane & 1;
        scr[wave][rp * 2 + cp] = acc;
        if (rp == 1) scr[wave][4 + cp] = tr;
    }
    if ((lane & 31) == 31) {
        int rp = lane >> 5;
        scr[wave][6 + rp] = tcpre;
        if (rp == 1) scr[wave][8] = xpre;
    }
    __syncthreads();
    if (lane < 16) {
        float out = 0.f;
        if (lane < 9) {
            int kh = lane / 3, kw = lane - kh * 3;
            int rp = (kh == 1) ? 0 : 1, cp = (kw == 1) ? 0 : 1;
            bool er = (kh == 0), ec = (kw == 0);
            const float* s = scr[wave];
            out = s[rp * 2 + cp];
            if (er) out -= s[4 + cp];
            if (ec) out -= s[6 + rp];
            if (er && ec) out += s[8];
        }
        vtb_write(vtb + (size_t)b * 16 * 1024, 1024 >> 5, lane, i, out);
    }
}

// c2: 81 masked sums over 64x64 (two stacked 3x3 s2 convs composed).
DEVINL float camU(const float* s, int p)
{
    int rc = p / 9, cc = p - rc * 9;
    int kh = rc / 3, kh2 = rc - kh * 3;
    int kw = cc / 3, kw2 = cc - kw * 3;
    int rm = (kh == 1) ? ((kh2 + 3) & 3) : (kh2 + 1);
    int cm = (kw == 1) ? ((kw2 + 3) & 3) : (kw2 + 1);
    bool er = (rc < 4), ec = (cc < 4);
    float u = s[rm * 4 + cm];
    if (er) u -= s[16 + (rm - 1) * 4 + cm];
    if (ec) u -= s[28 + rm * 3 + (cm - 1)];
    if (er && ec) u += s[40 + (rm - 1) * 3 + (cm - 1)];
    return u;
}

extern "C" __global__ __launch_bounds__(256)
void func_c2_kernel(const float* __restrict__ x, _Float16* __restrict__ vtb)
{
    __shared__ float scr[4][52];
    int wave = threadIdx.x >> 6, lane = threadIdx.x & 63;
    int idx = blockIdx.x * 4 + wave;            // [0, 8192)
    int b = idx >> 9, i = idx & 511;
    size_t base = (size_t)(b * 512 + i) * 4096;
    float acc[4] = {0.f, 0.f, 0.f, 0.f};
    float tr[3];
    for (int it = 0; it < 60; it += 4) {
#pragma unroll
        for (int rr = 0; rr < 4; ++rr)
            acc[rr] += x[base + (size_t)(it + rr) * 64 + lane];
    }
    acc[0] += x[base + 60 * 64 + lane];
#pragma unroll
    for (int rr = 1; rr < 4; ++rr) {
        float v = x[base + (size_t)(60 + rr) * 64 + lane];
        acc[rr] += v;
        tr[rr - 1] = v;
    }
    float tcx[4], xr[3];
#pragma unroll
    for (int g = 0; g < 4; ++g) tcx[g] = acc[g];
#pragma unroll
    for (int g = 0; g < 3; ++g) xr[g] = tr[g];
#pragma unroll
    for (int m = 4; m < 64; m <<= 1) {
#pragma unroll
        for (int g = 0; g < 4; ++g) acc[g] += __shfl_xor(acc[g], m);
#pragma unroll
        for (int g = 0; g < 3; ++g) tr[g] += __shfl_xor(tr[g], m);
    }
    if (lane < 4) {
#pragma unroll
        for (int rm = 0; rm < 4; ++rm) scr[wave][rm * 4 + lane] = acc[rm];
#pragma unroll
        for (int rx = 0; rx < 3; ++rx) scr[wave][16 + rx * 4 + lane] = tr[rx];
    }
    if (lane >= 61) {
        int cx = lane - 61;
#pragma unroll
        for (int rm = 0; rm < 4; ++rm) scr[wave][28 + rm * 3 + cx] = tcx[rm];
#pragma unroll
        for (int rx = 0; rx < 3; ++rx) scr[wave][40 + rx * 3 + cx] = xr[rx];
    }
    __syncthreads();
    const float* s = scr[wave];
    _Float16* vb = vtb + (size_t)b * 96 * 512;
    vtb_write(vb, 512 >> 5, lane, i, camU(s, lane));
    if (lane < 32) {
        int p = 64 + lane;
        vtb_write(vb, 512 >> 5, p, i, (p < 81) ? camU(s, p) : 0.f);
    }
}

// ---------------------------------------------------------------------------
// Stage 2: repack fp32 row-major -> blocked fp16 (16 rows x 256 cols / block).
// ---------------------------------------------------------------------------
extern "C" __global__ __launch_bounds__(256)
void repack_kernel(const float* __restrict__ c2, const float* __restrict__ c3,
                   const float* __restrict__ c4, _Float16* __restrict__ xb2,
                   _Float16* __restrict__ xb3, _Float16* __restrict__ xb4)
{
    __shared__ _Float16 T[16][264];
    int bid = blockIdx.x;
    const float* src; _Float16* dst; int N, grp, chunk;
    if (bid < 8192) { src = c2; dst = xb2; N = 4096; grp = bid >> 4; chunk = bid & 15; }
    else if (bid < 12288) { int id = bid - 8192; src = c3; dst = xb3; N = 1024; grp = id >> 2; chunk = id & 3; }
    else { src = c4; dst = xb4; N = 256; grp = bid - 12288; chunk = 0; }

    int tid = threadIdx.x;
    {
        int row = tid >> 4, t16 = tid & 15;
        const float* s = src + ((size_t)grp * 16 + row) * N + chunk * 256 + t16 * 16;
        float4 a = *(const float4*)(s + 0);
        float4 b = *(const float4*)(s + 4);
        float4 c = *(const float4*)(s + 8);
        float4 d = *(const float4*)(s + 12);
        h8 lo = {(_Float16)a.x, (_Float16)a.y, (_Float16)a.z, (_Float16)a.w,
                 (_Float16)b.x, (_Float16)b.y, (_Float16)b.z, (_Float16)b.w};
        h8 hi = {(_Float16)c.x, (_Float16)c.y, (_Float16)c.z, (_Float16)c.w,
                 (_Float16)d.x, (_Float16)d.y, (_Float16)d.z, (_Float16)d.w};
        *(h8*)&T[row][t16 * 16] = lo;
        *(h8*)&T[row][t16 * 16 + 8] = hi;
    }
    __syncthreads();
    int fl = tid >> 5, idx2 = tid & 31;
    size_t base = (size_t)grp * 16 * N + (size_t)(chunk * 8 + fl) * 512;
#pragma unroll
    for (int rep = 0; rep < 2; ++rep) {
        int idx = idx2 + rep * 32;
        int l16 = idx & 15, quad = idx >> 4;
        h8 v = *(h8*)&T[l16][fl * 32 + quad * 8];
        *(h8*)&dst[base + (size_t)idx * 8] = v;
    }
}

// ---------------------------------------------------------------------------
// Stage 3: barrier-free fused CAM flash.  att = softmax_d(-x x^T), F = g*attV+V
// ---------------------------------------------------------------------------
template <int N, int C, int PPAD, int RT>
DEVINL void flash_impl(const _Float16* __restrict__ xfb, const _Float16* __restrict__ vtb,
                       float* __restrict__ Fout, const float* __restrict__ gptr,
                       float* __restrict__ FoutD, int r0, _Float16* W16w)
{
    const int lane = threadIdx.x & 63;
    const int wave = threadIdx.x >> 6;
    const int l16 = lane & 15;
    const int quad = lane >> 4;
    const f4 fz = {0.f, 0.f, 0.f, 0.f};
    constexpr int KB = N >> 5;
    constexpr int CB = C >> 5;

    f4 accp[RT][PPAD / 16];
    float m_run[RT][4], l_run[RT][4];
#pragma unroll
    for (int rt = 0; rt < RT; ++rt) {
#pragma unroll
        for (int ct = 0; ct < PPAD / 16; ++ct) accp[rt][ct] = fz;
#pragma unroll
        for (int g = 0; g < 4; ++g) { m_run[rt][g] = -3.0e38f; l_run[rt][g] = 0.f; }
    }
    int arb[RT];
#pragma unroll
    for (int rt = 0; rt < RT; ++rt) arb[rt] = (r0 >> 4) + wave * RT + rt;

    for (int d0 = 0; d0 < C; d0 += 64) {
        f4 e[RT][4];
#pragma unroll
        for (int rt = 0; rt < RT; ++rt)
#pragma unroll
            for (int t = 0; t < 4; ++t) e[rt][t] = fz;

        for (int k0 = 0; k0 < N; k0 += 128) {
#pragma unroll
            for (int ks = 0; ks < 4; ++ks) {
                int kb = (k0 + ks * 32) >> 5;
                h8 a[RT];
#pragma unroll
                for (int rt = 0; rt < RT; ++rt)
                    a[rt] = *(const h8*)(xfb + ((size_t)arb[rt] * KB + kb) * 512 + lane * 8);
#pragma unroll
                for (int t = 0; t < 4; ++t) {
                    h8 bf = *(const h8*)(xfb + ((size_t)((d0 >> 4) + t) * KB + kb) * 512 + lane * 8);
#pragma unroll
                    for (int rt = 0; rt < RT; ++rt)
                        e[rt][t] = __builtin_amdgcn_mfma_f32_16x16x32_f16(a[rt], bf, e[rt][t], 0, 0, 0);
                }
            }
        }
        // online softmax over this 64-col tile; s = -energy
#pragma unroll
        for (int rt = 0; rt < RT; ++rt) {
            float mx[4], rs[4], al[4], mn[4];
#pragma unroll
            for (int g = 0; g < 4; ++g) {
                float v = -e[rt][0][g];
                v = fmaxf(v, -e[rt][1][g]);
                v = fmaxf(v, -e[rt][2][g]);
                v = fmaxf(v, -e[rt][3][g]);
                mx[g] = v;
            }
#pragma unroll
            for (int m = 1; m < 16; m <<= 1)
#pragma unroll
                for (int g = 0; g < 4; ++g) mx[g] = fmaxf(mx[g], __shfl_xor(mx[g], m));
#pragma unroll
            for (int g = 0; g < 4; ++g) {
                mn[g] = fmaxf(m_run[rt][g], mx[g]);
                al[g] = __expf(m_run[rt][g] - mn[g]);
                m_run[rt][g] = mn[g];
                rs[g] = 0.f;
            }
#pragma unroll
            for (int t = 0; t < 4; ++t)
#pragma unroll
                for (int g = 0; g < 4; ++g) {
                    float w = __expf(-e[rt][t][g] - mn[g]);
                    rs[g] += w;
                    W16w[(rt * 16 + quad * 4 + g) * 72 + l16 + 16 * t] = (_Float16)w;
                }
#pragma unroll
            for (int m = 1; m < 16; m <<= 1)
#pragma unroll
                for (int g = 0; g < 4; ++g) rs[g] += __shfl_xor(rs[g], m);
#pragma unroll
            for (int g = 0; g < 4; ++g) l_run[rt][g] = l_run[rt][g] * al[g] + rs[g];
#pragma unroll
            for (int ct = 0; ct < PPAD / 16; ++ct)
#pragma unroll
                for (int g = 0; g < 4; ++g) accp[rt][ct][g] *= al[g];
        }
        // projection: acc += W @ V (wave-private W in LDS, V fragments global)
#pragma unroll
        for (int kk = 0; kk < 64; kk += 32) {
            h8 wa[RT];
#pragma unroll
            for (int rt = 0; rt < RT; ++rt)
                wa[rt] = *(const h8*)&W16w[(rt * 16 + l16) * 72 + kk + quad * 8];
#pragma unroll
            for (int ct = 0; ct < PPAD / 16; ++ct) {
                h8 vb = *(const h8*)(vtb + ((size_t)ct * CB + ((d0 + kk) >> 5)) * 512 + lane * 8);
#pragma unroll
                for (int rt = 0; rt < RT; ++rt)
                    accp[rt][ct] = __builtin_amdgcn_mfma_f32_16x16x32_f16(wa[rt], vb, accp[rt][ct], 0, 0, 0);
            }
        }
    }
    float gamma = gptr[0];
#pragma unroll
    for (int rt = 0; rt < RT; ++rt)
#pragma unroll
        for (int ct = 0; ct < PPAD / 16; ++ct)
#pragma unroll
            for (int g = 0; g < 4; ++g) {
                int r = r0 + wave * 16 * RT + rt * 16 + quad * 4 + g;
                int p = ct * 16 + l16;
                float ident = (float)vtb[(((size_t)(p >> 4) * CB) + (r >> 5)) * 512
                                         + (size_t)(((r >> 3) & 3) * 16 + (p & 15)) * 8 + (r & 7)];
                float val = gamma * (accp[rt][ct][g] / l_run[rt][g]) + ident;
                Fout[(size_t)r * PPAD + p] = val;
                if (FoutD != nullptr && p == 0) FoutD[r] = val;
            }
}

extern "C" __global__ __launch_bounds__(256)
void flash_kernel(const _Float16* __restrict__ xb2, const _Float16* __restrict__ xb3,
                  const _Float16* __restrict__ xb4,
                  const _Float16* __restrict__ V2, const _Float16* __restrict__ V3,
                  const _Float16* __restrict__ V4,
                  float* __restrict__ F2, float* __restrict__ F3, float* __restrict__ F4,
                  float* __restrict__ F4d,
                  const float* __restrict__ g2, const float* __restrict__ g3,
                  const float* __restrict__ g4)
{
    __shared__ _Float16 W16[4 * 32 * 72];
    _Float16* W16w = &W16[(threadIdx.x >> 6) * 32 * 72];
    int bid = blockIdx.x;
    if (bid < 128) {                         // c2 heaviest first
        int b = bid >> 3, rb = bid & 7;
        flash_impl<4096, 512, 96, 1>(xb2 + (size_t)b * 512 * 4096, V2 + (size_t)b * 96 * 512,
                                     F2 + (size_t)b * 512 * 96, g2, nullptr, rb * 64, W16w);
    } else if (bid < 256) {                  // c3
        int x = bid - 128;
        int b = x >> 3, rb = x & 7;
        flash_impl<1024, 1024, 16, 2>(xb3 + (size_t)b * 1024 * 1024, V3 + (size_t)b * 16 * 1024,
                                      F3 + (size_t)b * 1024 * 16, g3, nullptr, rb * 128, W16w);
    } else {                                 // c4
        int x = bid - 256;
        int b = x >> 4, rb = x & 15;
        flash_impl<256, 2048, 16, 2>(xb4 + (size_t)b * 2048 * 256, V4 + (size_t)b * 16 * 2048,
                                     F4 + (size_t)b * 2048 * 16, g4, F4d + (size_t)b * 2048,
                                     rb * 128, W16w);
    }
}

// ---------------------------------------------------------------------------
// Stage 4: epilogues — one wave per output dot, all coalesced.
// ---------------------------------------------------------------------------

// V2m[b][j][k] = sum_{i,k2} w2a[j,i,k2]*F2[b,i,pp(k,k2)]
extern "C" __global__ __launch_bounds__(256)
void ep_v2_kernel(const float* __restrict__ F2, const float* __restrict__ w2a,
                  float* __restrict__ V2m)
{
    int wv = blockIdx.x * 4 + (threadIdx.x >> 6);  // [0, 8192)
    int lane = threadIdx.x & 63;
    int b = wv >> 9, j = wv & 511;
    float acc[9];
#pragma unroll
    for (int k = 0; k < 9; ++k) acc[k] = 0.f;
    for (int t = 0; t < 8; ++t) {
        int i = t * 64 + lane;
        const float* w = w2a + ((size_t)j * 512 + i) * 9;
        float wr[9];
#pragma unroll
        for (int k2 = 0; k2 < 9; ++k2) wr[k2] = w[k2];
        const float* F = F2 + ((size_t)b * 512 + i) * 96;
        float Fv[84];
#pragma unroll
        for (int q = 0; q < 21; ++q) *(float4*)&Fv[q * 4] = *(const float4*)&F[q * 4];
#pragma unroll
        for (int kh = 0; kh < 3; ++kh)
#pragma unroll
            for (int kh2 = 0; kh2 < 3; ++kh2)
#pragma unroll
                for (int kw = 0; kw < 3; ++kw)
#pragma unroll
                    for (int kw2 = 0; kw2 < 3; ++kw2)
                        acc[kh * 3 + kw] += wr[kh2 * 3 + kw2] * Fv[27 * kh + 9 * kh2 + 3 * kw + kw2];
    }
#pragma unroll
    for (int k = 0; k < 9; ++k)
#pragma unroll
        for (int m = 1; m < 64; m <<= 1) acc[k] += __shfl_xor(acc[k], m);
    if (lane < 9) V2m[((size_t)b * 512 + j) * 9 + lane] = acc[lane];
}

// pool A: pd4 + cam4 + raw-c4 tail
extern "C" __global__ __launch_bounds__(256)
void ep_pool_a_kernel(const float* __restrict__ V4d, const float* __restrict__ F4d,
                      const float* __restrict__ w4, const float* __restrict__ b4,
                      float* __restrict__ PD4, float* __restrict__ PF)
{
    int wv = blockIdx.x * 4 + (threadIdx.x >> 6);  // [0, 8704)
    int lane = threadIdx.x & 63;
    if (wv < 8192) {
        int b = wv >> 9, o = wv & 511;
        const float* wr = w4 + (size_t)o * 2048;
        const float* Vb = V4d + (size_t)b * 2048;
        const float* Fb = F4d + (size_t)b * 2048;
        float pd = 0.f, s = 0.f;
        for (int t = 0; t < 32; ++t) {
            int i = t * 64 + lane;
            float w = wr[i];
            pd += w * Vb[i];
            s += w * Fb[i];
        }
#pragma unroll
        for (int m = 1; m < 64; m <<= 1) { pd += __shfl_xor(pd, m); s += __shfl_xor(s, m); }
        if (lane == 0) {
            float pd4 = pd + b4[o];
            PD4[b * 512 + o] = pd4;
            PF[(size_t)b * 3584 + 1024 + o] = s + b4[o] + pd4;
        }
    } else {
        int idx = (wv - 8192) * 64 + lane;         // [0, 32768)
        int b = idx >> 11, i = idx & 2047;
        PF[(size_t)b * 3584 + 1536 + i] = V4d[(size_t)b * 2048 + i];
    }
}

// pool B: cam3 + cam2 (needs PD4)
extern "C" __global__ __launch_bounds__(256)
void ep_pool_b_kernel(const float* __restrict__ F3, const float* __restrict__ V2m,
                      const float* __restrict__ w3, const float* __restrict__ w2b,
                      const float* __restrict__ b2b, const float* __restrict__ PD4,
                      float* __restrict__ PF)
{
    int wv = blockIdx.x * 4 + (threadIdx.x >> 6);  // [0, 16384)
    int lane = threadIdx.x & 63;
    int half = wv >> 13, x = wv & 8191;
    int b = x >> 9, o = x & 511;
    float s = 0.f;
    if (half == 0) {                               // cam3
        const float* wr = w3 + (size_t)o * 9216;
        const float* Fb = F3 + (size_t)b * 1024 * 16;
        for (int t = 0; t < 144; ++t) {
            int kk = t * 64 + lane;
            int i = kk / 9, k = kk - 9 * i;
            s += wr[kk] * Fb[(size_t)i * 16 + k];
        }
#pragma unroll
        for (int m = 1; m < 64; m <<= 1) s += __shfl_xor(s, m);
        if (lane == 0)
            PF[(size_t)b * 3584 + 512 + o] = s * (1.f / 256.f) + PD4[b * 512 + o];
    } else {                                       // cam2
        const float* wr = w2b + (size_t)o * 4608;
        const float* Vb = V2m + (size_t)b * 4608;
        for (int t = 0; t < 72; ++t) {
            int kk = t * 64 + lane;
            s += wr[kk] * Vb[kk];
        }
#pragma unroll
        for (int m = 1; m < 64; m <<= 1) s += __shfl_xor(s, m);
        if (lane == 0)
            PF[(size_t)b * 3584 + o] = s * (1.f / 256.f) + b2b[o] + PD4[b * 512 + o];
    }
}

extern "C" __global__ __launch_bounds__(256)
void ep_fc_kernel(const float* __restrict__ PF, const float* __restrict__ fcw,
                  const float* __restrict__ fcb, float* __restrict__ out)
{
    __shared__ float r0s[256], r1s[256];
    int b = blockIdx.x, tid = threadIdx.x;
    float p0 = 0.f, p1 = 0.f;
    for (int k = tid; k < 3584; k += 256) {
        float f = PF[(size_t)b * 3584 + k];
        p0 += fcw[k] * f;
        p1 += fcw[3584 + k] * f;
    }
    r0s[tid] = p0;
    r1s[tid] = p1;
    __syncthreads();
    for (int s = 128; s > 0; s >>= 1) {
        if (tid < s) { r0s[tid] += r0s[tid + s]; r1s[tid] += r1s[tid + s]; }
        __syncthreads();
    }
    if (tid == 0) {
        out[b * 2 + 0] = r0s[0] + fcb[0];
        out[b * 2 + 1] = r1s[0] + fcb[1];
    }
}

// ---------------------------------------------------------------------------

extern "C" void kernel_launch(void* const* d_in, const int* in_sizes, int n_in,
                              void* d_out, int out_size, void* d_ws, size_t ws_size,
                              hipStream_t stream)
{
    const float* c2 = (const float*)d_in[0];
    const float* c3 = (const float*)d_in[1];
    const float* c4 = (const float*)d_in[2];
    const float* w4 = (const float*)d_in[3];
    const float* b4 = (const float*)d_in[4];
    const float* w3 = (const float*)d_in[5];
    const float* w2a = (const float*)d_in[6];
    const float* w2b = (const float*)d_in[7];
    const float* b2b = (const float*)d_in[8];
    const float* g2 = (const float*)d_in[9];
    const float* g3 = (const float*)d_in[10];
    const float* g4 = (const float*)d_in[11];
    const float* fcw = (const float*)d_in[12];
    const float* fcb = (const float*)d_in[13];
    float* out = (float*)d_out;

    char* ws = (char*)d_ws;
    size_t off = 0;
    auto carve = [&](size_t bytes) -> char* {
        char* p = ws + off;
        off += (bytes + 255) & ~(size_t)255;
        return p;
    };
    _Float16* xb2 = (_Float16*)carve(16ull * 512 * 4096 * 2);
    _Float16* xb3 = (_Float16*)carve(16ull * 1024 * 1024 * 2);
    _Float16* xb4 = (_Float16*)carve(16ull * 2048 * 256 * 2);
    _Float16* V2 = (_Float16*)carve(16ull * 96 * 512 * 2);
    _Float16* V3 = (_Float16*)carve(16ull * 16 * 1024 * 2);
    _Float16* V4 = (_Float16*)carve(16ull * 16 * 2048 * 2);
    float* V4d = (float*)carve(16ull * 2048 * 4);
    float* F2 = (float*)carve(16ull * 512 * 96 * 4);
    float* F3 = (float*)carve(16ull * 1024 * 16 * 4);
    float* F4 = (float*)carve(16ull * 2048 * 16 * 4);
    float* F4d = (float*)carve(16ull * 2048 * 4);
    float* V2m = (float*)carve(16ull * 512 * 9 * 4);
    float* PD4 = (float*)carve(16ull * 512 * 4);
    float* PF = (float*)carve(16ull * 3584 * 4);
    if (ws_size < off) return;  // workspace too small: fail visibly, no OOB

    func_c2_kernel<<<2048, 256, 0, stream>>>(c2, V2);
    func_c3_kernel<<<4096, 256, 0, stream>>>(c3, V3);
    func_c4_kernel<<<8192, 256, 0, stream>>>(c4, V4, V4d);
    repack_kernel<<<14336, 256, 0, stream>>>(c2, c3, c4, xb2, xb3, xb4);
    flash_kernel<<<512, 256, 0, stream>>>(xb2, xb3, xb4, V2, V3, V4,
                                          F2, F3, F4, F4d, g2, g3, g4);
    ep_v2_kernel<<<2048, 256, 0, stream>>>(F2, w2a, V2m);
    ep_pool_a_kernel<<<2176, 256, 0, stream>>>(V4d, F4d, w4, b4, PD4, PF);
    ep_pool_b_kernel<<<4096, 256, 0, stream>>>(F3, V2m, w3, w2b, b2b, PD4, PF);
    ep_fc_kernel<<<16, 256, 0, stream>>>(PF, fcw, fcb, out);
}

// Round 3
// 1129.772 us; speedup vs baseline: 1.6829x; 1.3742x over previous
//
#include <hip/hip_runtime.h>

typedef _Float16 h8 __attribute__((ext_vector_type(8)));
typedef float f4 __attribute__((ext_vector_type(4)));

#define DEVINL __device__ __forceinline__

// ---------------------------------------------------------------------------
// Blocked fp16 "frag layout" for mfma_f32_16x16x32_f16:
//   element (row r, k): frag_id = (r>>4)*(N>>5) + (k>>5),
//   within frag: half index = lane*8 + (k&7), lane = ((k>>3)&3)*16 + (r&15).
// One frag = 512 halves = 1 KB = one wave-wide dwordx4 (global or LDS).
// ---------------------------------------------------------------------------

DEVINL void gload_lds(const _Float16* g, _Float16* l)
{
    // per-lane global address; LDS base wave-uniform, HW writes lane*16B
    __builtin_amdgcn_global_load_lds(
        (const __attribute__((address_space(1))) void*)g,
        (__attribute__((address_space(3))) void*)l, 16, 0, 0);
}

// ---------------------------------------------------------------------------
// Stage 1: functional kernels (write V in frag layout; verified round 1/2).
// ---------------------------------------------------------------------------

DEVINL void vtb_write(_Float16* vtb, int CB, int p, int d, float v)
{
    size_t off = (((size_t)(p >> 4) * CB) + (d >> 5)) * 512
               + (size_t)(((d >> 3) & 3) * 16 + (p & 15)) * 8 + (d & 7);
    vtb[off] = (_Float16)v;
}

extern "C" __global__ __launch_bounds__(256)
void func_c4_kernel(const float* __restrict__ x, _Float16* __restrict__ vtb,
                    float* __restrict__ V4d)
{
    int wave = threadIdx.x >> 6, lane = threadIdx.x & 63;
    int idx = blockIdx.x * 4 + wave;            // [0, 32768)
    int b = idx >> 11, i = idx & 2047;
    size_t base = (size_t)(b * 2048 + i) * 256;
    float acc = 0.f;
#pragma unroll
    for (int it = 0; it < 4; ++it) acc += x[base + it * 64 + lane];
#pragma unroll
    for (int m = 1; m < 64; m <<= 1) acc += __shfl_xor(acc, m);
    float mean = acc * (1.f / 256.f);
    _Float16* vb = vtb + (size_t)b * 16 * 2048;
    if (lane < 16) vtb_write(vb, 2048 >> 5, lane, i, (lane == 0) ? mean : 0.f);
    if (lane == 0) V4d[b * 2048 + i] = mean;
}

extern "C" __global__ __launch_bounds__(256)
void func_c3_kernel(const float* __restrict__ x, _Float16* __restrict__ vtb)
{
    __shared__ float scr[4][12];
    int wave = threadIdx.x >> 6, lane = threadIdx.x & 63;
    int idx = blockIdx.x * 4 + wave;            // [0, 16384)
    int b = idx >> 10, i = idx & 1023;
    size_t base = (size_t)(b * 1024 + i) * 1024;
    float acc = 0.f;
    for (int it = 0; it < 15; ++it) acc += x[base + it * 64 + lane];
    float vl = x[base + 15 * 64 + lane];
    acc += vl;
    float tr = (lane >= 32) ? vl : 0.f;
    float tcpre = acc;
    float xpre = tr;
#pragma unroll
    for (int m = 2; m < 32; m <<= 1) {
        acc += __shfl_xor(acc, m);
        tr += __shfl_xor(tr, m);
    }
    if ((lane & 31) < 2) {
        int rp = lane >> 5, cp = lane & 1;
        scr[wave][rp * 2 + cp] = acc;
        if (rp == 1) scr[wave][4 + cp] = tr;
    }
    if ((lane & 31) == 31) {
        int rp = lane >> 5;
        scr[wave][6 + rp] = tcpre;
        if (rp == 1) scr[wave][8] = xpre;
    }
    __syncthreads();
    if (lane < 16) {
        float out = 0.f;
        if (lane < 9) {
            int kh = lane / 3, kw = lane - kh * 3;
            int rp = (kh == 1) ? 0 : 1, cp = (kw == 1) ? 0 : 1;
            bool er = (kh == 0), ec = (kw == 0);
            const float* s = scr[wave];
            out = s[rp * 2 + cp];
            if (er) out -= s[4 + cp];
            if (ec) out -= s[6 + rp];
            if (er && ec) out += s[8];
        }
        vtb_write(vtb + (size_t)b * 16 * 1024, 1024 >> 5, lane, i, out);
    }
}

DEVINL float camU(const float* s, int p)
{
    int rc = p / 9, cc = p - rc * 9;
    int kh = rc / 3, kh2 = rc - kh * 3;
    int kw = cc / 3, kw2 = cc - kw * 3;
    int rm = (kh == 1) ? ((kh2 + 3) & 3) : (kh2 + 1);
    int cm = (kw == 1) ? ((kw2 + 3) & 3) : (kw2 + 1);
    bool er = (rc < 4), ec = (cc < 4);
    float u = s[rm * 4 + cm];
    if (er) u -= s[16 + (rm - 1) * 4 + cm];
    if (ec) u -= s[28 + rm * 3 + (cm - 1)];
    if (er && ec) u += s[40 + (rm - 1) * 3 + (cm - 1)];
    return u;
}

extern "C" __global__ __launch_bounds__(256)
void func_c2_kernel(const float* __restrict__ x, _Float16* __restrict__ vtb)
{
    __shared__ float scr[4][52];
    int wave = threadIdx.x >> 6, lane = threadIdx.x & 63;
    int idx = blockIdx.x * 4 + wave;            // [0, 8192)
    int b = idx >> 9, i = idx & 511;
    size_t base = (size_t)(b * 512 + i) * 4096;
    float acc[4] = {0.f, 0.f, 0.f, 0.f};
    float tr[3];
    for (int it = 0; it < 60; it += 4) {
#pragma unroll
        for (int rr = 0; rr < 4; ++rr)
            acc[rr] += x[base + (size_t)(it + rr) * 64 + lane];
    }
    acc[0] += x[base + 60 * 64 + lane];
#pragma unroll
    for (int rr = 1; rr < 4; ++rr) {
        float v = x[base + (size_t)(60 + rr) * 64 + lane];
        acc[rr] += v;
        tr[rr - 1] = v;
    }
    float tcx[4], xr[3];
#pragma unroll
    for (int g = 0; g < 4; ++g) tcx[g] = acc[g];
#pragma unroll
    for (int g = 0; g < 3; ++g) xr[g] = tr[g];
#pragma unroll
    for (int m = 4; m < 64; m <<= 1) {
#pragma unroll
        for (int g = 0; g < 4; ++g) acc[g] += __shfl_xor(acc[g], m);
#pragma unroll
        for (int g = 0; g < 3; ++g) tr[g] += __shfl_xor(tr[g], m);
    }
    if (lane < 4) {
#pragma unroll
        for (int rm = 0; rm < 4; ++rm) scr[wave][rm * 4 + lane] = acc[rm];
#pragma unroll
        for (int rx = 0; rx < 3; ++rx) scr[wave][16 + rx * 4 + lane] = tr[rx];
    }
    if (lane >= 61) {
        int cx = lane - 61;
#pragma unroll
        for (int rm = 0; rm < 4; ++rm) scr[wave][28 + rm * 3 + cx] = tcx[rm];
#pragma unroll
        for (int rx = 0; rx < 3; ++rx) scr[wave][40 + rx * 3 + cx] = xr[rx];
    }
    __syncthreads();
    const float* s = scr[wave];
    _Float16* vb = vtb + (size_t)b * 96 * 512;
    vtb_write(vb, 512 >> 5, lane, i, camU(s, lane));
    if (lane < 32) {
        int p = 64 + lane;
        vtb_write(vb, 512 >> 5, p, i, (p < 81) ? camU(s, p) : 0.f);
    }
}

// ---------------------------------------------------------------------------
// Stage 2: repack fp32 row-major -> blocked fp16.
// ---------------------------------------------------------------------------
extern "C" __global__ __launch_bounds__(256)
void repack_kernel(const float* __restrict__ c2, const float* __restrict__ c3,
                   const float* __restrict__ c4, _Float16* __restrict__ xb2,
                   _Float16* __restrict__ xb3, _Float16* __restrict__ xb4)
{
    __shared__ _Float16 T[16][264];
    int bid = blockIdx.x;
    const float* src; _Float16* dst; int N, grp, chunk;
    if (bid < 8192) { src = c2; dst = xb2; N = 4096; grp = bid >> 4; chunk = bid & 15; }
    else if (bid < 12288) { int id = bid - 8192; src = c3; dst = xb3; N = 1024; grp = id >> 2; chunk = id & 3; }
    else { src = c4; dst = xb4; N = 256; grp = bid - 12288; chunk = 0; }

    int tid = threadIdx.x;
    {
        int row = tid >> 4, t16 = tid & 15;
        const float* s = src + ((size_t)grp * 16 + row) * N + chunk * 256 + t16 * 16;
        float4 a = *(const float4*)(s + 0);
        float4 b = *(const float4*)(s + 4);
        float4 c = *(const float4*)(s + 8);
        float4 d = *(const float4*)(s + 12);
        h8 lo = {(_Float16)a.x, (_Float16)a.y, (_Float16)a.z, (_Float16)a.w,
                 (_Float16)b.x, (_Float16)b.y, (_Float16)b.z, (_Float16)b.w};
        h8 hi = {(_Float16)c.x, (_Float16)c.y, (_Float16)c.z, (_Float16)c.w,
                 (_Float16)d.x, (_Float16)d.y, (_Float16)d.z, (_Float16)d.w};
        *(h8*)&T[row][t16 * 16] = lo;
        *(h8*)&T[row][t16 * 16 + 8] = hi;
    }
    __syncthreads();
    int fl = tid >> 5, idx2 = tid & 31;
    size_t base = (size_t)grp * 16 * N + (size_t)(chunk * 8 + fl) * 512;
#pragma unroll
    for (int rep = 0; rep < 2; ++rep) {
        int idx = idx2 + rep * 32;
        int l16 = idx & 15, quad = idx >> 4;
        h8 v = *(h8*)&T[l16][fl * 32 + quad * 8];
        *(h8*)&dst[base + (size_t)idx * 8] = v;
    }
}

// ---------------------------------------------------------------------------
// Stage 3: fused CAM flash — LDS-staged double-buffered K-loop, XCD-affine.
// Block = 4 waves x 32 rows = 128 rows; d-tile = 128 cols; chunk = 32 k.
// MODE 0: c2 partial (write raw acc+m,l); 1: c3 final F; 2: c4 dense-p0 only.
// ---------------------------------------------------------------------------
template <int N, int C, int PPAD, int DSTEPS, int MODE>
DEVINL void flash3(const _Float16* __restrict__ xfb, const _Float16* __restrict__ vtb,
                   float* __restrict__ Pout, float* __restrict__ Pml,
                   const float* __restrict__ gptr, float* __restrict__ FoutD,
                   int r0, int c0, _Float16* SA, _Float16* SB, _Float16* SW)
{
    constexpr int KB = N >> 5;
    constexpr int CB = C >> 5;
    constexpr int LOG = (KB == 128) ? 7 : ((KB == 32) ? 5 : 3);
    constexpr int TOT = DSTEPS * KB;
    constexpr int PT = PPAD / 16;
    const int lane = threadIdx.x & 63;
    const int wave = threadIdx.x >> 6;
    const int l16 = lane & 15;
    const int quad = lane >> 4;
    const f4 fz = {0.f, 0.f, 0.f, 0.f};

    f4 e[2][8];
    f4 accp[2][PT];
    float m_run[2][4], l_run[2][4];
#pragma unroll
    for (int rt = 0; rt < 2; ++rt) {
#pragma unroll
        for (int pt = 0; pt < PT; ++pt) accp[rt][pt] = fz;
#pragma unroll
        for (int g = 0; g < 4; ++g) { m_run[rt][g] = -3.0e38f; l_run[rt][g] = 0.f; }
    }

    auto issue = [&](int ch) {
        int buf = ch & 1;
        int kb = ch & (KB - 1);
        int d0 = c0 + (ch >> LOG) * 128;
        int id = wave * 4;
#pragma unroll
        for (int u = 0; u < 4; ++u) {
            int iid = id + u;
            int isB = iid >> 3;
            int fr = iid & 7;
            int frow = (isB ? (d0 >> 4) : (r0 >> 4)) + fr;
            const _Float16* src = xfb + ((size_t)frow * KB + kb) * 512 + lane * 8;
            _Float16* dst = (isB ? SB : SA) + (size_t)(buf * 8 + fr) * 512;
            gload_lds(src, dst);
        }
    };

    issue(0);
    for (int ch = 0; ch < TOT; ++ch) {
        __syncthreads();   // drains own vmcnt -> chunk ch staged for all waves
        if (ch + 1 < TOT) issue(ch + 1);
        int buf = ch & 1;
        if ((ch & (KB - 1)) == 0) {
#pragma unroll
            for (int rt = 0; rt < 2; ++rt)
#pragma unroll
                for (int ct = 0; ct < 8; ++ct) e[rt][ct] = fz;
        }
        h8 a0 = *(const h8*)&SA[(size_t)(buf * 8 + wave * 2 + 0) * 512 + lane * 8];
        h8 a1 = *(const h8*)&SA[(size_t)(buf * 8 + wave * 2 + 1) * 512 + lane * 8];
#pragma unroll
        for (int ct = 0; ct < 8; ++ct) {
            h8 bf = *(const h8*)&SB[(size_t)(buf * 8 + ct) * 512 + lane * 8];
            e[0][ct] = __builtin_amdgcn_mfma_f32_16x16x32_f16(a0, bf, e[0][ct], 0, 0, 0);
            e[1][ct] = __builtin_amdgcn_mfma_f32_16x16x32_f16(a1, bf, e[1][ct], 0, 0, 0);
        }
        if ((ch & (KB - 1)) == KB - 1) {
            int dd0 = c0 + (ch >> LOG) * 128;
            // online softmax over this 128-col tile (s = -energy) + W@V proj
#pragma unroll
            for (int rt = 0; rt < 2; ++rt) {
                float mx[4];
#pragma unroll
                for (int g = 0; g < 4; ++g) {
                    float v = -e[rt][0][g];
#pragma unroll
                    for (int ct = 1; ct < 8; ++ct) v = fmaxf(v, -e[rt][ct][g]);
                    mx[g] = v;
                }
#pragma unroll
                for (int m = 1; m < 16; m <<= 1)
#pragma unroll
                    for (int g = 0; g < 4; ++g) mx[g] = fmaxf(mx[g], __shfl_xor(mx[g], m));
                float al[4], rs[4];
#pragma unroll
                for (int g = 0; g < 4; ++g) {
                    float mn = fmaxf(m_run[rt][g], mx[g]);
                    al[g] = __expf(m_run[rt][g] - mn);
                    m_run[rt][g] = mn;
                    rs[g] = 0.f;
                }
#pragma unroll
                for (int pt = 0; pt < PT; ++pt)
#pragma unroll
                    for (int g = 0; g < 4; ++g) accp[rt][pt][g] *= al[g];
#pragma unroll
                for (int ph = 0; ph < 2; ++ph) {
#pragma unroll
                    for (int c4i = 0; c4i < 4; ++c4i) {
                        int ct = ph * 4 + c4i;
#pragma unroll
                        for (int g = 0; g < 4; ++g) {
                            float w = __expf(-e[rt][ct][g] - m_run[rt][g]);
                            rs[g] += w;
                            SW[(size_t)(rt * 2 + (c4i >> 1)) * 512 +
                               (size_t)(((c4i & 1) * 2 + (l16 >> 3)) * 16 + quad * 4 + g) * 8 +
                               (l16 & 7)] = (_Float16)w;
                        }
                    }
#pragma unroll
                    for (int kc = 0; kc < 2; ++kc) {
                        h8 wa = *(const h8*)&SW[(size_t)(rt * 2 + kc) * 512 + lane * 8];
                        int kbv = (dd0 + ph * 64 + kc * 32) >> 5;
#pragma unroll
                        for (int pt = 0; pt < PT; ++pt) {
                            h8 vb = *(const h8*)(vtb + ((size_t)pt * CB + kbv) * 512 + lane * 8);
                            accp[rt][pt] = __builtin_amdgcn_mfma_f32_16x16x32_f16(wa, vb, accp[rt][pt], 0, 0, 0);
                        }
                    }
                }
#pragma unroll
                for (int m = 1; m < 16; m <<= 1)
#pragma unroll
                    for (int g = 0; g < 4; ++g) rs[g] += __shfl_xor(rs[g], m);
#pragma unroll
                for (int g = 0; g < 4; ++g) l_run[rt][g] = l_run[rt][g] * al[g] + rs[g];
            }
        }
    }
    // epilogue
    if (MODE == 0) {
#pragma unroll
        for (int rt = 0; rt < 2; ++rt)
#pragma unroll
            for (int pt = 0; pt < PT; ++pt)
#pragma unroll
                for (int g = 0; g < 4; ++g) {
                    int row = r0 + wave * 32 + rt * 16 + quad * 4 + g;
                    int p = pt * 16 + l16;
                    Pout[(size_t)row * PPAD + p] = accp[rt][pt][g];
                }
        if (l16 == 0) {
#pragma unroll
            for (int rt = 0; rt < 2; ++rt)
#pragma unroll
                for (int g = 0; g < 4; ++g) {
                    int row = r0 + wave * 32 + rt * 16 + quad * 4 + g;
                    Pml[row * 2 + 0] = m_run[rt][g];
                    Pml[row * 2 + 1] = l_run[rt][g];
                }
        }
    } else {
        float gamma = gptr[0];
#pragma unroll
        for (int rt = 0; rt < 2; ++rt)
#pragma unroll
            for (int pt = 0; pt < PT; ++pt)
#pragma unroll
                for (int g = 0; g < 4; ++g) {
                    int row = r0 + wave * 32 + rt * 16 + quad * 4 + g;
                    int p = pt * 16 + l16;
                    float ident = (float)vtb[((size_t)(p >> 4) * CB + (row >> 5)) * 512
                                             + (size_t)(((row >> 3) & 3) * 16 + (p & 15)) * 8 + (row & 7)];
                    float val = gamma * (accp[rt][pt][g] / l_run[rt][g]) + ident;
                    if (MODE == 1) Pout[(size_t)row * PPAD + p] = val;
                    else if (p == 0) FoutD[row] = val;
                }
    }
}

extern "C" __global__ __launch_bounds__(256)
void flash_kernel(const _Float16* __restrict__ xb2, const _Float16* __restrict__ xb3,
                  const _Float16* __restrict__ xb4,
                  const _Float16* __restrict__ V2, const _Float16* __restrict__ V3,
                  const _Float16* __restrict__ V4,
                  float* __restrict__ F2, float* __restrict__ Pacc1,
                  float* __restrict__ Pml2,
                  float* __restrict__ F3, float* __restrict__ F4d,
                  const float* __restrict__ g2, const float* __restrict__ g3,
                  const float* __restrict__ g4)
{
    __shared__ _Float16 SA[16 * 512];     // 16 KB (2 bufs x 8 frags)
    __shared__ _Float16 SB[16 * 512];     // 16 KB
    __shared__ _Float16 SW[4 * 2048];     // 16 KB (per-wave W phase frags)
    _Float16* SWw = &SW[(threadIdx.x >> 6) * 2048];
    int bid = blockIdx.x;
    int xcd = bid & 7, slot = bid >> 3;   // same (level,batch) -> same XCD for L2 reuse
    if (slot < 16) {                      // c2: 2-way d-split, partial outputs
        int b = xcd + ((slot >= 8) ? 8 : 0);
        int u = slot & 7, rb = u >> 1, s = u & 1;
        float* Pa = (s == 0 ? F2 : Pacc1) + (size_t)b * 512 * 96;
        flash3<4096, 512, 96, 2, 0>(xb2 + (size_t)b * 512 * 4096, V2 + (size_t)b * 96 * 512,
                                    Pa, Pml2 + (size_t)(b * 2 + s) * 512 * 2, g2, nullptr,
                                    rb * 128, s * 256, SA, SB, SWw);
    } else if (slot < 32) {               // c3: full sweep, direct F3
        int t = slot - 16;
        int b = xcd + ((t >= 8) ? 8 : 0);
        int rb = t & 7;
        flash3<1024, 1024, 16, 8, 1>(xb3 + (size_t)b * 1024 * 1024, V3 + (size_t)b * 16 * 1024,
                                     F3 + (size_t)b * 1024 * 16, nullptr, g3, nullptr,
                                     rb * 128, 0, SA, SB, SWw);
    } else {                              // c4: full sweep, dense p0 only
        int t = slot - 32;
        int b = xcd + ((t >= 16) ? 8 : 0);
        int rb = t & 15;
        flash3<256, 2048, 16, 16, 2>(xb4 + (size_t)b * 2048 * 256, V4 + (size_t)b * 16 * 2048,
                                     nullptr, nullptr, g4, F4d + (size_t)b * 2048,
                                     rb * 128, 0, SA, SB, SWw);
    }
}

// merge the two c2 d-split partials -> final F2 (in place over partial 0)
extern "C" __global__ __launch_bounds__(256)
void merge_c2_kernel(float* __restrict__ F2, const float* __restrict__ Pacc1,
                     const float* __restrict__ Pml2, const _Float16* __restrict__ V2,
                     const float* __restrict__ g2)
{
    int wv = blockIdx.x * 4 + (threadIdx.x >> 6);   // [0, 8192)
    int lane = threadIdx.x & 63;
    int b = wv >> 9, r = wv & 511;
    const float* ml = Pml2 + (size_t)b * 2 * 512 * 2;
    float m0 = ml[r * 2], l0 = ml[r * 2 + 1];
    float m1 = ml[(512 + r) * 2], l1 = ml[(512 + r) * 2 + 1];
    float M = fmaxf(m0, m1);
    float w0 = __expf(m0 - M), w1 = __expf(m1 - M);
    float L = l0 * w0 + l1 * w1;
    float g = g2[0];
    float* P0 = F2 + ((size_t)b * 512 + r) * 96;
    const float* P1 = Pacc1 + ((size_t)b * 512 + r) * 96;
    const _Float16* vb = V2 + (size_t)b * 96 * 512;
#pragma unroll
    for (int rep = 0; rep < 2; ++rep) {
        int p = lane + rep * 64;
        if (p < 96) {
            float acc = P0[p] * w0 + P1[p] * w1;
            float ident = (float)vb[((size_t)(p >> 4) * 16 + (r >> 5)) * 512
                                    + (size_t)(((r >> 3) & 3) * 16 + (p & 15)) * 8 + (r & 7)];
            P0[p] = g * (acc / L) + ident;
        }
    }
}

// ---------------------------------------------------------------------------
// Stage 4: epilogues.
// ---------------------------------------------------------------------------

// block per j: w2a[j] staged in LDS once; waves cover 16 batches
extern "C" __global__ __launch_bounds__(256)
void ep_v2_kernel(const float* __restrict__ F2, const float* __restrict__ w2a,
                  float* __restrict__ V2m)
{
    __shared__ float W[4608];
    int j = blockIdx.x;
    for (int t = threadIdx.x; t < 4608; t += 256) W[t] = w2a[(size_t)j * 4608 + t];
    __syncthreads();
    int wave = threadIdx.x >> 6, lane = threadIdx.x & 63;
    for (int bb = 0; bb < 4; ++bb) {
        int b = wave * 4 + bb;
        float acc[9];
#pragma unroll
        for (int k = 0; k < 9; ++k) acc[k] = 0.f;
        for (int t = 0; t < 8; ++t) {
            int i = t * 64 + lane;
            float wr[9];
#pragma unroll
            for (int k2 = 0; k2 < 9; ++k2) wr[k2] = W[i * 9 + k2];
            const float* F = F2 + ((size_t)b * 512 + i) * 96;
            float Fv[84];
#pragma unroll
            for (int q = 0; q < 21; ++q) *(float4*)&Fv[q * 4] = *(const float4*)&F[q * 4];
#pragma unroll
            for (int kh = 0; kh < 3; ++kh)
#pragma unroll
                for (int kh2 = 0; kh2 < 3; ++kh2)
#pragma unroll
                    for (int kw = 0; kw < 3; ++kw)
#pragma unroll
                        for (int kw2 = 0; kw2 < 3; ++kw2)
                            acc[kh * 3 + kw] += wr[kh2 * 3 + kw2] * Fv[27 * kh + 9 * kh2 + 3 * kw + kw2];
        }
#pragma unroll
        for (int k = 0; k < 9; ++k)
#pragma unroll
            for (int m = 1; m < 64; m <<= 1) acc[k] += __shfl_xor(acc[k], m);
        if (lane < 9) V2m[((size_t)b * 512 + j) * 9 + lane] = acc[lane];
    }
}

// pool A: pd4 + cam4 + raw-c4 tail (wave per dot)
extern "C" __global__ __launch_bounds__(256)
void ep_pool_a_kernel(const float* __restrict__ V4d, const float* __restrict__ F4d,
                      const float* __restrict__ w4, const float* __restrict__ b4,
                      float* __restrict__ PD4, float* __restrict__ PF)
{
    int wv = blockIdx.x * 4 + (threadIdx.x >> 6);  // [0, 8704)
    int lane = threadIdx.x & 63;
    if (wv < 8192) {
        int b = wv >> 9, o = wv & 511;
        const float* wr = w4 + (size_t)o * 2048;
        const float* Vb = V4d + (size_t)b * 2048;
        const float* Fb = F4d + (size_t)b * 2048;
        float pd = 0.f, s = 0.f;
        for (int t = 0; t < 32; ++t) {
            int i = t * 64 + lane;
            float w = wr[i];
            pd += w * Vb[i];
            s += w * Fb[i];
        }
#pragma unroll
        for (int m = 1; m < 64; m <<= 1) { pd += __shfl_xor(pd, m); s += __shfl_xor(s, m); }
        if (lane == 0) {
            float pd4 = pd + b4[o];
            PD4[b * 512 + o] = pd4;
            PF[(size_t)b * 3584 + 1024 + o] = s + b4[o] + pd4;
        }
    } else {
        int idx = (wv - 8192) * 64 + lane;         // [0, 32768)
        int b = idx >> 11, i = idx & 2047;
        PF[(size_t)b * 3584 + 1536 + i] = V4d[(size_t)b * 2048 + i];
    }
}

// pool B: block per output channel; weight row staged in LDS once
extern "C" __global__ __launch_bounds__(256)
void ep_pool_b_kernel(const float* __restrict__ F3, const float* __restrict__ V2m,
                      const float* __restrict__ w3, const float* __restrict__ w2b,
                      const float* __restrict__ b2b, const float* __restrict__ PD4,
                      float* __restrict__ PF)
{
    __shared__ float W[9216];
    int bid = blockIdx.x;
    int wave = threadIdx.x >> 6, lane = threadIdx.x & 63;
    if (bid < 512) {                               // cam3
        int o = bid;
        for (int t = threadIdx.x; t < 9216; t += 256) W[t] = w3[(size_t)o * 9216 + t];
        __syncthreads();
        for (int bb = 0; bb < 4; ++bb) {
            int b = wave * 4 + bb;
            float s = 0.f;
            for (int t = 0; t < 144; ++t) {
                int kk = t * 64 + lane;
                int i = kk / 9, k = kk - 9 * i;
                s += W[kk] * F3[((size_t)b * 1024 + i) * 16 + k];
            }
#pragma unroll
            for (int m = 1; m < 64; m <<= 1) s += __shfl_xor(s, m);
            if (lane == 0)
                PF[(size_t)b * 3584 + 512 + o] = s * (1.f / 256.f) + PD4[b * 512 + o];
        }
    } else {                                       // cam2
        int o = bid - 512;
        for (int t = threadIdx.x; t < 4608; t += 256) W[t] = w2b[(size_t)o * 4608 + t];
        __syncthreads();
        for (int bb = 0; bb < 4; ++bb) {
            int b = wave * 4 + bb;
            float s = 0.f;
            for (int t = 0; t < 72; ++t) {
                int kk = t * 64 + lane;
                s += W[kk] * V2m[(size_t)b * 4608 + kk];
            }
#pragma unroll
            for (int m = 1; m < 64; m <<= 1) s += __shfl_xor(s, m);
            if (lane == 0)
                PF[(size_t)b * 3584 + o] = s * (1.f / 256.f) + b2b[o] + PD4[b * 512 + o];
        }
    }
}

extern "C" __global__ __launch_bounds__(256)
void ep_fc_kernel(const float* __restrict__ PF, const float* __restrict__ fcw,
                  const float* __restrict__ fcb, float* __restrict__ out)
{
    __shared__ float r0s[256], r1s[256];
    int b = blockIdx.x, tid = threadIdx.x;
    float p0 = 0.f, p1 = 0.f;
    for (int k = tid; k < 3584; k += 256) {
        float f = PF[(size_t)b * 3584 + k];
        p0 += fcw[k] * f;
        p1 += fcw[3584 + k] * f;
    }
    r0s[tid] = p0;
    r1s[tid] = p1;
    __syncthreads();
    for (int s = 128; s > 0; s >>= 1) {
        if (tid < s) { r0s[tid] += r0s[tid + s]; r1s[tid] += r1s[tid + s]; }
        __syncthreads();
    }
    if (tid == 0) {
        out[b * 2 + 0] = r0s[0] + fcb[0];
        out[b * 2 + 1] = r1s[0] + fcb[1];
    }
}

// ---------------------------------------------------------------------------

extern "C" void kernel_launch(void* const* d_in, const int* in_sizes, int n_in,
                              void* d_out, int out_size, void* d_ws, size_t ws_size,
                              hipStream_t stream)
{
    const float* c2 = (const float*)d_in[0];
    const float* c3 = (const float*)d_in[1];
    const float* c4 = (const float*)d_in[2];
    const float* w4 = (const float*)d_in[3];
    const float* b4 = (const float*)d_in[4];
    const float* w3 = (const float*)d_in[5];
    const float* w2a = (const float*)d_in[6];
    const float* w2b = (const float*)d_in[7];
    const float* b2b = (const float*)d_in[8];
    const float* g2 = (const float*)d_in[9];
    const float* g3 = (const float*)d_in[10];
    const float* g4 = (const float*)d_in[11];
    const float* fcw = (const float*)d_in[12];
    const float* fcb = (const float*)d_in[13];
    float* out = (float*)d_out;

    char* ws = (char*)d_ws;
    size_t off = 0;
    auto carve = [&](size_t bytes) -> char* {
        char* p = ws + off;
        off += (bytes + 255) & ~(size_t)255;
        return p;
    };
    _Float16* xb2 = (_Float16*)carve(16ull * 512 * 4096 * 2);
    _Float16* xb3 = (_Float16*)carve(16ull * 1024 * 1024 * 2);
    _Float16* xb4 = (_Float16*)carve(16ull * 2048 * 256 * 2);
    _Float16* V2 = (_Float16*)carve(16ull * 96 * 512 * 2);
    _Float16* V3 = (_Float16*)carve(16ull * 16 * 1024 * 2);
    _Float16* V4 = (_Float16*)carve(16ull * 16 * 2048 * 2);
    float* V4d = (float*)carve(16ull * 2048 * 4);
    float* F2 = (float*)carve(16ull * 512 * 96 * 4);     // doubles as c2 partial 0
    float* Pacc1 = (float*)carve(16ull * 512 * 96 * 4);  // c2 partial 1
    float* Pml2 = (float*)carve(16ull * 2 * 512 * 2 * 4);
    float* F3 = (float*)carve(16ull * 1024 * 16 * 4);
    float* F4d = (float*)carve(16ull * 2048 * 4);
    float* V2m = (float*)carve(16ull * 512 * 9 * 4);
    float* PD4 = (float*)carve(16ull * 512 * 4);
    float* PF = (float*)carve(16ull * 3584 * 4);
    if (ws_size < off) return;  // workspace too small: fail visibly, no OOB

    repack_kernel<<<14336, 256, 0, stream>>>(c2, c3, c4, xb2, xb3, xb4);
    func_c2_kernel<<<2048, 256, 0, stream>>>(c2, V2);
    func_c3_kernel<<<4096, 256, 0, stream>>>(c3, V3);
    func_c4_kernel<<<8192, 256, 0, stream>>>(c4, V4, V4d);
    flash_kernel<<<512, 256, 0, stream>>>(xb2, xb3, xb4, V2, V3, V4,
                                          F2, Pacc1, Pml2, F3, F4d, g2, g3, g4);
    merge_c2_kernel<<<2048, 256, 0, stream>>>(F2, Pacc1, Pml2, V2, g2);
    ep_v2_kernel<<<512, 256, 0, stream>>>(F2, w2a, V2m);
    ep_pool_a_kernel<<<2176, 256, 0, stream>>>(V4d, F4d, w4, b4, PD4, PF);
    ep_pool_b_kernel<<<1024, 256, 0, stream>>>(F3, V2m, w3, w2b, b2b, PD4, PF);
    ep_fc_kernel<<<16, 256, 0, stream>>>(PF, fcw, fcb, out);
}

// Round 4
// 993.691 us; speedup vs baseline: 1.9134x; 1.1369x over previous
//
#include <hip/hip_runtime.h>

typedef _Float16 h8 __attribute__((ext_vector_type(8)));
typedef float f4 __attribute__((ext_vector_type(4)));

#define DEVINL __device__ __forceinline__

// ---------------------------------------------------------------------------
// frag layout (mfma_f32_16x16x32_f16): element (row r, k):
//   frag = (r>>4)*(K>>5) + (k>>5); lane = ((k>>3)&3)*16 + (r&15); idx = k&7.
// One frag = 512 halves = 1 KB = one wave-wide dwordx4.
// ---------------------------------------------------------------------------

DEVINL void gload_lds(const _Float16* g, _Float16* l)
{
    __builtin_amdgcn_global_load_lds(
        (const __attribute__((address_space(1))) void*)g,
        (__attribute__((address_space(3))) void*)l, 16, 0, 0);
}

// ---------------------------------------------------------------------------
// Stage 1: functional kernels (verified rounds 1-3).
// ---------------------------------------------------------------------------

DEVINL void vtb_write(_Float16* vtb, int CB, int p, int d, float v)
{
    size_t off = (((size_t)(p >> 4) * CB) + (d >> 5)) * 512
               + (size_t)(((d >> 3) & 3) * 16 + (p & 15)) * 8 + (d & 7);
    vtb[off] = (_Float16)v;
}

extern "C" __global__ __launch_bounds__(256)
void func_c4_kernel(const float* __restrict__ x, _Float16* __restrict__ vtb,
                    float* __restrict__ V4d)
{
    int wave = threadIdx.x >> 6, lane = threadIdx.x & 63;
    int idx = blockIdx.x * 4 + wave;
    int b = idx >> 11, i = idx & 2047;
    size_t base = (size_t)(b * 2048 + i) * 256;
    float acc = 0.f;
#pragma unroll
    for (int it = 0; it < 4; ++it) acc += x[base + it * 64 + lane];
#pragma unroll
    for (int m = 1; m < 64; m <<= 1) acc += __shfl_xor(acc, m);
    float mean = acc * (1.f / 256.f);
    _Float16* vb = vtb + (size_t)b * 16 * 2048;
    if (lane < 16) vtb_write(vb, 64, lane, i, (lane == 0) ? mean : 0.f);
    if (lane == 0) V4d[b * 2048 + i] = mean;
}

extern "C" __global__ __launch_bounds__(256)
void func_c3_kernel(const float* __restrict__ x, _Float16* __restrict__ vtb)
{
    __shared__ float scr[4][12];
    int wave = threadIdx.x >> 6, lane = threadIdx.x & 63;
    int idx = blockIdx.x * 4 + wave;
    int b = idx >> 10, i = idx & 1023;
    size_t base = (size_t)(b * 1024 + i) * 1024;
    float acc = 0.f;
    for (int it = 0; it < 15; ++it) acc += x[base + it * 64 + lane];
    float vl = x[base + 15 * 64 + lane];
    acc += vl;
    float tr = (lane >= 32) ? vl : 0.f;
    float tcpre = acc;
    float xpre = tr;
#pragma unroll
    for (int m = 2; m < 32; m <<= 1) {
        acc += __shfl_xor(acc, m);
        tr += __shfl_xor(tr, m);
    }
    if ((lane & 31) < 2) {
        int rp = lane >> 5, cp = lane & 1;
        scr[wave][rp * 2 + cp] = acc;
        if (rp == 1) scr[wave][4 + cp] = tr;
    }
    if ((lane & 31) == 31) {
        int rp = lane >> 5;
        scr[wave][6 + rp] = tcpre;
        if (rp == 1) scr[wave][8] = xpre;
    }
    __syncthreads();
    if (lane < 16) {
        float out = 0.f;
        if (lane < 9) {
            int kh = lane / 3, kw = lane - kh * 3;
            int rp = (kh == 1) ? 0 : 1, cp = (kw == 1) ? 0 : 1;
            bool er = (kh == 0), ec = (kw == 0);
            const float* s = scr[wave];
            out = s[rp * 2 + cp];
            if (er) out -= s[4 + cp];
            if (ec) out -= s[6 + rp];
            if (er && ec) out += s[8];
        }
        vtb_write(vtb + (size_t)b * 16 * 1024, 32, lane, i, out);
    }
}

DEVINL float camU(const float* s, int p)
{
    int rc = p / 9, cc = p - rc * 9;
    int kh = rc / 3, kh2 = rc - kh * 3;
    int kw = cc / 3, kw2 = cc - kw * 3;
    int rm = (kh == 1) ? ((kh2 + 3) & 3) : (kh2 + 1);
    int cm = (kw == 1) ? ((kw2 + 3) & 3) : (kw2 + 1);
    bool er = (rc < 4), ec = (cc < 4);
    float u = s[rm * 4 + cm];
    if (er) u -= s[16 + (rm - 1) * 4 + cm];
    if (ec) u -= s[28 + rm * 3 + (cm - 1)];
    if (er && ec) u += s[40 + (rm - 1) * 3 + (cm - 1)];
    return u;
}

extern "C" __global__ __launch_bounds__(256)
void func_c2_kernel(const float* __restrict__ x, _Float16* __restrict__ vtb)
{
    __shared__ float scr[4][52];
    int wave = threadIdx.x >> 6, lane = threadIdx.x & 63;
    int idx = blockIdx.x * 4 + wave;
    int b = idx >> 9, i = idx & 511;
    size_t base = (size_t)(b * 512 + i) * 4096;
    float acc[4] = {0.f, 0.f, 0.f, 0.f};
    float tr[3];
    for (int it = 0; it < 60; it += 4) {
#pragma unroll
        for (int rr = 0; rr < 4; ++rr)
            acc[rr] += x[base + (size_t)(it + rr) * 64 + lane];
    }
    acc[0] += x[base + 60 * 64 + lane];
#pragma unroll
    for (int rr = 1; rr < 4; ++rr) {
        float v = x[base + (size_t)(60 + rr) * 64 + lane];
        acc[rr] += v;
        tr[rr - 1] = v;
    }
    float tcx[4], xr[3];
#pragma unroll
    for (int g = 0; g < 4; ++g) tcx[g] = acc[g];
#pragma unroll
    for (int g = 0; g < 3; ++g) xr[g] = tr[g];
#pragma unroll
    for (int m = 4; m < 64; m <<= 1) {
#pragma unroll
        for (int g = 0; g < 4; ++g) acc[g] += __shfl_xor(acc[g], m);
#pragma unroll
        for (int g = 0; g < 3; ++g) tr[g] += __shfl_xor(tr[g], m);
    }
    if (lane < 4) {
#pragma unroll
        for (int rm = 0; rm < 4; ++rm) scr[wave][rm * 4 + lane] = acc[rm];
#pragma unroll
        for (int rx = 0; rx < 3; ++rx) scr[wave][16 + rx * 4 + lane] = tr[rx];
    }
    if (lane >= 61) {
        int cx = lane - 61;
#pragma unroll
        for (int rm = 0; rm < 4; ++rm) scr[wave][28 + rm * 3 + cx] = tcx[rm];
#pragma unroll
        for (int rx = 0; rx < 3; ++rx) scr[wave][40 + rx * 3 + cx] = xr[rx];
    }
    __syncthreads();
    const float* s = scr[wave];
    _Float16* vb = vtb + (size_t)b * 96 * 512;
    vtb_write(vb, 16, lane, i, camU(s, lane));
    if (lane < 32) {
        int p = 64 + lane;
        vtb_write(vb, 16, p, i, (p < 81) ? camU(s, p) : 0.f);
    }
}

// ---------------------------------------------------------------------------
// Stage 2: repack fp32 row-major -> frag fp16 (generic 16 rows x 256 cols).
// ---------------------------------------------------------------------------
DEVINL void repack_tile(const float* __restrict__ src, _Float16* __restrict__ dst,
                        int K, int grp, int chunk, _Float16 (*T)[264])
{
    int tid = threadIdx.x;
    {
        int row = tid >> 4, t16 = tid & 15;
        const float* s = src + ((size_t)grp * 16 + row) * K + chunk * 256 + t16 * 16;
        float4 a = *(const float4*)(s + 0);
        float4 b = *(const float4*)(s + 4);
        float4 c = *(const float4*)(s + 8);
        float4 d = *(const float4*)(s + 12);
        h8 lo = {(_Float16)a.x, (_Float16)a.y, (_Float16)a.z, (_Float16)a.w,
                 (_Float16)b.x, (_Float16)b.y, (_Float16)b.z, (_Float16)b.w};
        h8 hi = {(_Float16)c.x, (_Float16)c.y, (_Float16)c.z, (_Float16)c.w,
                 (_Float16)d.x, (_Float16)d.y, (_Float16)d.z, (_Float16)d.w};
        *(h8*)&T[row][t16 * 16] = lo;
        *(h8*)&T[row][t16 * 16 + 8] = hi;
    }
    __syncthreads();
    int fl = tid >> 5, idx2 = tid & 31;
    size_t base = (size_t)grp * 16 * K + (size_t)(chunk * 8 + fl) * 512;
#pragma unroll
    for (int rep = 0; rep < 2; ++rep) {
        int idx = idx2 + rep * 32;
        int l16 = idx & 15, quad = idx >> 4;
        h8 v = *(h8*)&T[l16][fl * 32 + quad * 8];
        *(h8*)&dst[base + (size_t)idx * 8] = v;
    }
}

extern "C" __global__ __launch_bounds__(256)
void repack_kernel(const float* __restrict__ c2, const float* __restrict__ c3,
                   const float* __restrict__ c4, _Float16* __restrict__ xb2,
                   _Float16* __restrict__ xb3, _Float16* __restrict__ xb4)
{
    __shared__ _Float16 T[16][264];
    int bid = blockIdx.x;
    const float* src; _Float16* dst; int K, grp, chunk;
    if (bid < 8192) { src = c2; dst = xb2; K = 4096; grp = bid >> 4; chunk = bid & 15; }
    else if (bid < 12288) { int id = bid - 8192; src = c3; dst = xb3; K = 1024; grp = id >> 2; chunk = id & 3; }
    else { src = c4; dst = xb4; K = 256; grp = bid - 12288; chunk = 0; }
    repack_tile(src, dst, K, grp, chunk, T);
}

extern "C" __global__ __launch_bounds__(256)
void repack_w_kernel(const float* __restrict__ w4, const float* __restrict__ w3,
                     const float* __restrict__ w2a, const float* __restrict__ w2b,
                     _Float16* __restrict__ w4f, _Float16* __restrict__ w3f,
                     _Float16* __restrict__ w2af, _Float16* __restrict__ w2bf)
{
    __shared__ _Float16 T[16][264];
    int bid = blockIdx.x;
    const float* src; _Float16* dst; int K, grp, chunk;
    if (bid < 256) { src = w4; dst = w4f; K = 2048; grp = bid >> 3; chunk = bid & 7; }
    else if (bid < 1408) { int t = bid - 256; src = w3; dst = w3f; K = 9216; grp = t / 36; chunk = t - 36 * (t / 36); }
    else if (bid < 1984) { int t = bid - 1408; src = w2a; dst = w2af; K = 4608; grp = t / 18; chunk = t - 18 * (t / 18); }
    else { int t = bid - 1984; src = w2b; dst = w2bf; K = 4608; grp = t / 18; chunk = t - 18 * (t / 18); }
    repack_tile(src, dst, K, grp, chunk, T);
}

// ---------------------------------------------------------------------------
// Stage 3: fused CAM flash. 4 waves x 64 rows = 256-row blocks, 128-col d-tiles.
// A-frags global->VGPR (wave-private, 1-chunk register prefetch); B via
// global_load_lds double buffer; 1 barrier/chunk, 32 MFMA/chunk/wave.
// MODE 1: c3 -> final F3 dense.  MODE 2: c4 -> dense p0 (F4d) only.
// MODE 3: c2 -> per-tile exp weights Wg (frag fp16) + per-tile (m,l) stats.
// ---------------------------------------------------------------------------
template <int N, int C, int DT, int MODE>
DEVINL void flash4(const _Float16* __restrict__ xfb, const _Float16* __restrict__ vtb,
                   float* __restrict__ Fout, float* __restrict__ FoutD,
                   _Float16* __restrict__ Wg, float* __restrict__ Sml,
                   const float* __restrict__ gptr, int r0, int c0,
                   _Float16* SB, _Float16* SWw)
{
    constexpr int KB = N >> 5;
    const int lane = threadIdx.x & 63;
    const int wave = threadIdx.x >> 6;
    const int l16 = lane & 15, quad = lane >> 4;
    const f4 fz = {0.f, 0.f, 0.f, 0.f};
    const size_t loff = (size_t)lane * 8;

    const _Float16* Abase = xfb + (size_t)((r0 >> 4) + wave * 4) * KB * 512 + loff;

    f4 accp[4];
    float m_run[4][4], l_run[4][4];
#pragma unroll
    for (int rt = 0; rt < 4; ++rt) {
        accp[rt] = fz;
#pragma unroll
        for (int g = 0; g < 4; ++g) { m_run[rt][g] = -3.0e38f; l_run[rt][g] = 0.f; }
    }

    h8 acur[4], anxt[4];
#pragma unroll
    for (int rt = 0; rt < 4; ++rt)
        acur[rt] = *(const h8*)(Abase + (size_t)rt * KB * 512);
    {
        int fr = wave * 2;
#pragma unroll
        for (int u = 0; u < 2; ++u)
            gload_lds(xfb + (size_t)(((c0 >> 4) + fr + u) * KB) * 512 + loff,
                      SB + ((size_t)(fr + u) << 9));
    }

    for (int dt = 0; dt < DT; ++dt) {
        const int d0 = c0 + dt * 128;
        f4 e[4][8];
#pragma unroll
        for (int rt = 0; rt < 4; ++rt)
#pragma unroll
            for (int ct = 0; ct < 8; ++ct) e[rt][ct] = fz;

#pragma unroll 2
        for (int kc = 0; kc < KB; ++kc) {
            const int buf = kc & 1;
            __syncthreads();
            if (!((dt == DT - 1) && (kc == KB - 1))) {
                int nkb = (kc == KB - 1) ? 0 : kc + 1;
                int nd0 = (kc == KB - 1) ? d0 + 128 : d0;
                int fr = wave * 2;
#pragma unroll
                for (int u = 0; u < 2; ++u)
                    gload_lds(xfb + (size_t)(((nd0 >> 4) + fr + u) * KB + nkb) * 512 + loff,
                              SB + ((size_t)((buf ^ 1) * 8 + fr + u) << 9));
#pragma unroll
                for (int rt = 0; rt < 4; ++rt)
                    anxt[rt] = *(const h8*)(Abase + ((size_t)rt * KB + nkb) * 512);
            }
#pragma unroll
            for (int ct = 0; ct < 8; ++ct) {
                h8 bf = *(const h8*)&SB[((size_t)(buf * 8 + ct) << 9) + loff];
#pragma unroll
                for (int rt = 0; rt < 4; ++rt)
                    e[rt][ct] = __builtin_amdgcn_mfma_f32_16x16x32_f16(acur[rt], bf, e[rt][ct], 0, 0, 0);
            }
#pragma unroll
            for (int rt = 0; rt < 4; ++rt) acur[rt] = anxt[rt];
        }

        // per-tile softmax (s = -energy)
#pragma unroll
        for (int rt = 0; rt < 4; ++rt) {
            float mx[4];
#pragma unroll
            for (int g = 0; g < 4; ++g) {
                float v = -e[rt][0][g];
#pragma unroll
                for (int ct = 1; ct < 8; ++ct) v = fmaxf(v, -e[rt][ct][g]);
                mx[g] = v;
            }
#pragma unroll
            for (int m = 1; m < 16; m <<= 1)
#pragma unroll
                for (int g = 0; g < 4; ++g) mx[g] = fmaxf(mx[g], __shfl_xor(mx[g], m));
            float mref[4], al[4];
            if (MODE != 3) {
#pragma unroll
                for (int g = 0; g < 4; ++g) {
                    float nm = fmaxf(m_run[rt][g], mx[g]);
                    al[g] = __expf(m_run[rt][g] - nm);
                    m_run[rt][g] = nm;
                    mref[g] = nm;
                    accp[rt][g] *= al[g];
                }
            } else {
#pragma unroll
                for (int g = 0; g < 4; ++g) mref[g] = mx[g];
            }
            float rs[4] = {0.f, 0.f, 0.f, 0.f};
#pragma unroll
            for (int ct = 0; ct < 8; ++ct) {
#pragma unroll
                for (int g = 0; g < 4; ++g) {
                    float w = __expf(-e[rt][ct][g] - mref[g]);
                    rs[g] += w;
                    int lane2 = ((ct * 2 + (l16 >> 3)) & 3) * 16 + quad * 4 + g;
                    SWw[((ct >> 1) << 9) + lane2 * 8 + (l16 & 7)] = (_Float16)w;
                }
            }
#pragma unroll
            for (int kc2 = 0; kc2 < 4; ++kc2) {
                h8 wa = *(const h8*)&SWw[((size_t)kc2 << 9) + loff];
                if (MODE == 3) {
                    int tile = (c0 >> 7) + dt;
                    int rfrag = (r0 >> 4) + wave * 4 + rt;
                    *(h8*)&Wg[((size_t)((tile * 32 + rfrag) * 4 + kc2) << 9) + loff] = wa;
                } else {
                    h8 vb = *(const h8*)(vtb + (((size_t)(d0 >> 5) + kc2) << 9) + loff);
                    accp[rt] = __builtin_amdgcn_mfma_f32_16x16x32_f16(wa, vb, accp[rt], 0, 0, 0);
                }
            }
#pragma unroll
            for (int m = 1; m < 16; m <<= 1)
#pragma unroll
                for (int g = 0; g < 4; ++g) rs[g] += __shfl_xor(rs[g], m);
            if (MODE == 3) {
                if (l16 == 0) {
                    int tile = (c0 >> 7) + dt;
#pragma unroll
                    for (int g = 0; g < 4; ++g) {
                        int row = r0 + wave * 64 + rt * 16 + quad * 4 + g;
                        Sml[((size_t)tile * 512 + row) * 2 + 0] = mref[g];
                        Sml[((size_t)tile * 512 + row) * 2 + 1] = rs[g];
                    }
                }
            } else {
#pragma unroll
                for (int g = 0; g < 4; ++g)
                    l_run[rt][g] = l_run[rt][g] * al[g] + rs[g];
            }
        }
    }
    if (MODE == 1) {
        float gam = gptr[0];
#pragma unroll
        for (int rt = 0; rt < 4; ++rt)
#pragma unroll
            for (int g = 0; g < 4; ++g) {
                int row = r0 + wave * 64 + rt * 16 + quad * 4 + g;
                float ident = (float)vtb[(size_t)(row >> 5) * 512
                               + (size_t)(((row >> 3) & 3) * 16 + l16) * 8 + (row & 7)];
                Fout[(size_t)row * 16 + l16] = gam * (accp[rt][g] / l_run[rt][g]) + ident;
            }
    } else if (MODE == 2) {
        float gam = gptr[0];
        if (l16 == 0) {
#pragma unroll
            for (int rt = 0; rt < 4; ++rt)
#pragma unroll
                for (int g = 0; g < 4; ++g) {
                    int row = r0 + wave * 64 + rt * 16 + quad * 4 + g;
                    float ident = (float)vtb[(size_t)(row >> 5) * 512
                                   + (size_t)(((row >> 3) & 3) * 16) * 8 + (row & 7)];
                    FoutD[row] = gam * (accp[rt][g] / l_run[rt][g]) + ident;
                }
        }
    }
}

extern "C" __global__ __launch_bounds__(256, 2)
void flash_kernel(const _Float16* __restrict__ xb2, const _Float16* __restrict__ xb3,
                  const _Float16* __restrict__ xb4,
                  const _Float16* __restrict__ V3, const _Float16* __restrict__ V4,
                  _Float16* __restrict__ Wg, float* __restrict__ Sml,
                  float* __restrict__ F3, float* __restrict__ F4d,
                  const float* __restrict__ g3, const float* __restrict__ g4)
{
    __shared__ _Float16 SB[16 * 512];
    __shared__ _Float16 SW[4 * 4 * 512];
    _Float16* SWw = &SW[(threadIdx.x >> 6) * 4 * 512];
    int bid = blockIdx.x;
    if (bid < 64) {                         // c2: MODE 3, 2x2 (row, d) split
        int xcd = bid & 7, s = bid >> 3;
        int b = xcd + 8 * (s & 1), unit = s >> 1;
        int rb = unit & 1, ds = unit >> 1;
        flash4<4096, 512, 2, 3>(xb2 + (size_t)b * 512 * 4096, nullptr, nullptr, nullptr,
                                Wg + (size_t)b * 262144, Sml + (size_t)b * 4096, nullptr,
                                rb * 256, ds * 256, SB, SWw);
    } else if (bid < 128) {                 // c3: MODE 1
        int t = bid - 64, xcd = t & 7, s = t >> 3;
        int b = xcd + 8 * (s & 1), rb = s >> 1;
        flash4<1024, 1024, 8, 1>(xb3 + (size_t)b * 1024 * 1024, V3 + (size_t)b * 16 * 1024,
                                 F3 + (size_t)b * 1024 * 16, nullptr, nullptr, nullptr, g3,
                                 rb * 256, 0, SB, SWw);
    } else {                                // c4: MODE 2
        int t = bid - 128, xcd = t & 7, s = t >> 3;
        int b = xcd + 8 * (s & 1), rb = s >> 1;
        flash4<256, 2048, 16, 2>(xb4 + (size_t)b * 2048 * 256, V4 + (size_t)b * 16 * 2048,
                                 nullptr, F4d + (size_t)b * 2048, nullptr, nullptr, g4,
                                 rb * 256, 0, SB, SWw);
    }
}

// ---------------------------------------------------------------------------
// Stage 4: c2 deferred projection: F2 = g2*(softmax@V2)+V2 from Wg + stats.
// ---------------------------------------------------------------------------
extern "C" __global__ __launch_bounds__(256)
void proj_c2_kernel(const _Float16* __restrict__ Wg, const float* __restrict__ Sml,
                    const _Float16* __restrict__ V2, const float* __restrict__ g2,
                    float* __restrict__ F2)
{
    int b = blockIdx.x >> 2, rb = blockIdx.x & 3;
    int lane = threadIdx.x & 63, wave = threadIdx.x >> 6;
    int l16 = lane & 15, quad = lane >> 4;
    size_t loff = (size_t)lane * 8;
    const _Float16* Wb = Wg + (size_t)b * 262144;
    const float* Sb = Sml + (size_t)b * 4096;
    const _Float16* Vb = V2 + (size_t)b * 96 * 512;
    const f4 fz = {0.f, 0.f, 0.f, 0.f};
    f4 accP[2][6];
    float M[2][4], L[2][4];
#pragma unroll
    for (int rt = 0; rt < 2; ++rt) {
#pragma unroll
        for (int pt = 0; pt < 6; ++pt) accP[rt][pt] = fz;
#pragma unroll
        for (int g = 0; g < 4; ++g) { M[rt][g] = -3.0e38f; L[rt][g] = 0.f; }
    }
    for (int t = 0; t < 4; ++t) {
        f4 tmp[2][6];
#pragma unroll
        for (int rt = 0; rt < 2; ++rt)
#pragma unroll
            for (int pt = 0; pt < 6; ++pt) tmp[rt][pt] = fz;
#pragma unroll
        for (int kb = 0; kb < 4; ++kb) {
            h8 wa[2];
#pragma unroll
            for (int rt = 0; rt < 2; ++rt) {
                int rfrag = rb * 8 + wave * 2 + rt;
                wa[rt] = *(const h8*)&Wb[((size_t)((t * 32 + rfrag) * 4 + kb) << 9) + loff];
            }
#pragma unroll
            for (int pt = 0; pt < 6; ++pt) {
                h8 vb = *(const h8*)&Vb[((size_t)(pt * 16 + t * 4 + kb) << 9) + loff];
#pragma unroll
                for (int rt = 0; rt < 2; ++rt)
                    tmp[rt][pt] = __builtin_amdgcn_mfma_f32_16x16x32_f16(wa[rt], vb, tmp[rt][pt], 0, 0, 0);
            }
        }
#pragma unroll
        for (int rt = 0; rt < 2; ++rt)
#pragma unroll
            for (int g = 0; g < 4; ++g) {
                int row = (rb * 8 + wave * 2 + rt) * 16 + quad * 4 + g;
                float mt = Sb[((size_t)t * 512 + row) * 2 + 0];
                float lt = Sb[((size_t)t * 512 + row) * 2 + 1];
                float nm = fmaxf(M[rt][g], mt);
                float ao = __expf(M[rt][g] - nm);
                float at = __expf(mt - nm);
#pragma unroll
                for (int pt = 0; pt < 6; ++pt)
                    accP[rt][pt][g] = accP[rt][pt][g] * ao + at * tmp[rt][pt][g];
                L[rt][g] = L[rt][g] * ao + at * lt;
                M[rt][g] = nm;
            }
    }
    float gam = g2[0];
#pragma unroll
    for (int rt = 0; rt < 2; ++rt)
#pragma unroll
        for (int pt = 0; pt < 6; ++pt)
#pragma unroll
            for (int g = 0; g < 4; ++g) {
                int row = (rb * 8 + wave * 2 + rt) * 16 + quad * 4 + g;
                int p = pt * 16 + l16;
                float ident = (float)Vb[((size_t)pt * 16 + (row >> 5)) * 512
                               + (size_t)(((row >> 3) & 3) * 16 + (p & 15)) * 8 + (row & 7)];
                F2[((size_t)b * 512 + row) * 96 + p] = gam * (accP[rt][pt][g] / L[rt][g]) + ident;
            }
}

// ---------------------------------------------------------------------------
// Stage 5: gather activations into B-frag fp16 tensors for epilogue GEMMs.
// ---------------------------------------------------------------------------
extern "C" __global__ __launch_bounds__(256)
void gather1_kernel(const float* __restrict__ F2, const float* __restrict__ F3,
                    const float* __restrict__ V4d, const float* __restrict__ F4d,
                    _Float16* __restrict__ G, _Float16* __restrict__ XB3,
                    _Float16* __restrict__ XB4)
{
    int gid = blockIdx.x * 256 + threadIdx.x;
    int lane = gid & 63, fragid = gid >> 6;
    int kq = lane >> 4, n16 = lane & 15;
    _Float16 v[8];
    if (fragid < 1296) {                    // G[(i,k2)][(b,kcol)]
        int nb = fragid / 144, kb = fragid - nb * 144;
        int n = nb * 16 + n16;
        int b = n / 9, kcol = n - b * 9;
        int kh = kcol / 3, kw = kcol - kh * 3;
#pragma unroll
        for (int j = 0; j < 8; ++j) {
            int K = kb * 32 + kq * 8 + j;
            int i = K / 9, k2 = K - i * 9;
            int kh2 = k2 / 3, kw2 = k2 - kh2 * 3;
            int p = (kh * 3 + kh2) * 9 + kw * 3 + kw2;
            v[j] = (_Float16)F2[((size_t)b * 512 + i) * 96 + p];
        }
        *(h8*)&G[((size_t)fragid << 9) + lane * 8] = *(h8*)v;
    } else if (fragid < 1584) {             // XB3[(i,k)][b]
        int kb = fragid - 1296;
#pragma unroll
        for (int j = 0; j < 8; ++j) {
            int K = kb * 32 + kq * 8 + j;
            int i = K / 9, k9 = K - i * 9;
            v[j] = (_Float16)F3[((size_t)n16 * 1024 + i) * 16 + k9];
        }
        *(h8*)&XB3[((size_t)kb << 9) + lane * 8] = *(h8*)v;
    } else {                                // XB4[i][(b,which)]
        int f = fragid - 1584;
        int nb = f >> 6, kb = f & 63;
        const float* src = nb ? F4d : V4d;
#pragma unroll
        for (int j = 0; j < 8; ++j) {
            int i = kb * 32 + kq * 8 + j;
            v[j] = (_Float16)src[(size_t)n16 * 2048 + i];
        }
        *(h8*)&XB4[((size_t)f << 9) + lane * 8] = *(h8*)v;
    }
}

extern "C" __global__ __launch_bounds__(256)
void gather2_kernel(const float* __restrict__ V2m, _Float16* __restrict__ XB2)
{
    int gid = blockIdx.x * 256 + threadIdx.x;   // 144 frags x 64 lanes
    int lane = gid & 63, kb = gid >> 6;
    int kq = lane >> 4, b = lane & 15;
    _Float16 v[8];
#pragma unroll
    for (int j = 0; j < 8; ++j) {
        int K = kb * 32 + kq * 8 + j;
        int jj = K / 9, k = K - jj * 9;
        v[j] = (_Float16)V2m[((size_t)b * 512 + jj) * 9 + k];
    }
    *(h8*)&XB2[((size_t)kb << 9) + lane * 8] = *(h8*)v;
}

// ---------------------------------------------------------------------------
// Stage 6: epilogue GEMMs (MFMA).
// ---------------------------------------------------------------------------
extern "C" __global__ __launch_bounds__(256)
void ep_gemm1_kernel(const _Float16* __restrict__ w2af, const _Float16* __restrict__ G,
                     const _Float16* __restrict__ w3f, const _Float16* __restrict__ XB3,
                     const _Float16* __restrict__ w4f, const _Float16* __restrict__ XB4,
                     float* __restrict__ V2m, float* __restrict__ raw3,
                     float* __restrict__ raw4)
{
    int lane = threadIdx.x & 63, wave = threadIdx.x >> 6;
    int l16 = lane & 15, quad = lane >> 4;
    size_t loff = (size_t)lane * 8;
    const f4 fz = {0.f, 0.f, 0.f, 0.f};
    int bid = blockIdx.x;
    if (bid < 8) {                          // V2m = w2a @ G   (N=144)
        int mt = bid * 4 + wave;
        f4 acc[9];
#pragma unroll
        for (int nb = 0; nb < 9; ++nb) acc[nb] = fz;
        for (int kf = 0; kf < 144; ++kf) {
            h8 a = *(const h8*)&w2af[(((size_t)mt * 144 + kf) << 9) + loff];
#pragma unroll
            for (int nb = 0; nb < 9; ++nb) {
                h8 bfr = *(const h8*)&G[(((size_t)nb * 144 + kf) << 9) + loff];
                acc[nb] = __builtin_amdgcn_mfma_f32_16x16x32_f16(a, bfr, acc[nb], 0, 0, 0);
            }
        }
#pragma unroll
        for (int nb = 0; nb < 9; ++nb)
#pragma unroll
            for (int g = 0; g < 4; ++g) {
                int j = mt * 16 + quad * 4 + g;
                int n = nb * 16 + l16;
                int b = n / 9, k = n - b * 9;
                V2m[((size_t)b * 512 + j) * 9 + k] = acc[nb][g];
            }
    } else if (bid < 16) {                  // raw3 = w3 @ XB3  (N=16)
        int mt = (bid - 8) * 4 + wave;
        f4 acc = fz;
        for (int kf = 0; kf < 288; ++kf) {
            h8 a = *(const h8*)&w3f[(((size_t)mt * 288 + kf) << 9) + loff];
            h8 bfr = *(const h8*)&XB3[((size_t)kf << 9) + loff];
            acc = __builtin_amdgcn_mfma_f32_16x16x32_f16(a, bfr, acc, 0, 0, 0);
        }
#pragma unroll
        for (int g = 0; g < 4; ++g)
            raw3[(size_t)(mt * 16 + quad * 4 + g) * 16 + l16] = acc[g];
    } else {                                // raw4 = w4 @ [V4d|F4d]  (N=32)
        int mt = (bid - 16) * 4 + wave;
        f4 acc[2] = {fz, fz};
        for (int kf = 0; kf < 64; ++kf) {
            h8 a = *(const h8*)&w4f[(((size_t)mt * 64 + kf) << 9) + loff];
#pragma unroll
            for (int nb = 0; nb < 2; ++nb) {
                h8 bfr = *(const h8*)&XB4[(((size_t)nb * 64 + kf) << 9) + loff];
                acc[nb] = __builtin_amdgcn_mfma_f32_16x16x32_f16(a, bfr, acc[nb], 0, 0, 0);
            }
        }
#pragma unroll
        for (int nb = 0; nb < 2; ++nb)
#pragma unroll
            for (int g = 0; g < 4; ++g)
                raw4[((size_t)nb * 512 + mt * 16 + quad * 4 + g) * 16 + l16] = acc[nb][g];
    }
}

extern "C" __global__ __launch_bounds__(256)
void ep_gemm2_kernel(const _Float16* __restrict__ w2bf, const _Float16* __restrict__ XB2,
                     float* __restrict__ raw2)
{
    int lane = threadIdx.x & 63, wave = threadIdx.x >> 6;
    int l16 = lane & 15, quad = lane >> 4;
    size_t loff = (size_t)lane * 8;
    int mt = blockIdx.x * 4 + wave;
    f4 acc = {0.f, 0.f, 0.f, 0.f};
    for (int kf = 0; kf < 144; ++kf) {
        h8 a = *(const h8*)&w2bf[(((size_t)mt * 144 + kf) << 9) + loff];
        h8 bfr = *(const h8*)&XB2[((size_t)kf << 9) + loff];
        acc = __builtin_amdgcn_mfma_f32_16x16x32_f16(a, bfr, acc, 0, 0, 0);
    }
#pragma unroll
    for (int g = 0; g < 4; ++g)
        raw2[(size_t)(mt * 16 + quad * 4 + g) * 16 + l16] = acc[g];
}

// ---------------------------------------------------------------------------
// Stage 7: PF assembly + FC, fused.
// ---------------------------------------------------------------------------
extern "C" __global__ __launch_bounds__(256)
void final_kernel(const float* __restrict__ raw2, const float* __restrict__ raw3,
                  const float* __restrict__ raw4, const float* __restrict__ V4d,
                  const float* __restrict__ b4, const float* __restrict__ b2b,
                  const float* __restrict__ fcw, const float* __restrict__ fcb,
                  float* __restrict__ out)
{
    __shared__ float pf[3584];
    __shared__ float r0s[256], r1s[256];
    int b = blockIdx.x, tid = threadIdx.x;
    for (int o = tid; o < 512; o += 256) {
        float pd4 = raw4[(size_t)o * 16 + b] + b4[o];
        pf[1024 + o] = raw4[(size_t)(512 + o) * 16 + b] + b4[o] + pd4;
        pf[512 + o] = raw3[(size_t)o * 16 + b] * (1.f / 256.f) + pd4;
        pf[o] = raw2[(size_t)o * 16 + b] * (1.f / 256.f) + b2b[o] + pd4;
    }
    for (int i = tid; i < 2048; i += 256) pf[1536 + i] = V4d[(size_t)b * 2048 + i];
    __syncthreads();
    float p0 = 0.f, p1 = 0.f;
    for (int k = tid; k < 3584; k += 256) {
        float f = pf[k];
        p0 += fcw[k] * f;
        p1 += fcw[3584 + k] * f;
    }
    r0s[tid] = p0;
    r1s[tid] = p1;
    __syncthreads();
    for (int s = 128; s > 0; s >>= 1) {
        if (tid < s) { r0s[tid] += r0s[tid + s]; r1s[tid] += r1s[tid + s]; }
        __syncthreads();
    }
    if (tid == 0) {
        out[b * 2 + 0] = r0s[0] + fcb[0];
        out[b * 2 + 1] = r1s[0] + fcb[1];
    }
}

// ---------------------------------------------------------------------------

extern "C" void kernel_launch(void* const* d_in, const int* in_sizes, int n_in,
                              void* d_out, int out_size, void* d_ws, size_t ws_size,
                              hipStream_t stream)
{
    const float* c2 = (const float*)d_in[0];
    const float* c3 = (const float*)d_in[1];
    const float* c4 = (const float*)d_in[2];
    const float* w4 = (const float*)d_in[3];
    const float* b4 = (const float*)d_in[4];
    const float* w3 = (const float*)d_in[5];
    const float* w2a = (const float*)d_in[6];
    const float* w2b = (const float*)d_in[7];
    const float* b2b = (const float*)d_in[8];
    const float* g2 = (const float*)d_in[9];
    const float* g3 = (const float*)d_in[10];
    const float* g4 = (const float*)d_in[11];
    const float* fcw = (const float*)d_in[12];
    const float* fcb = (const float*)d_in[13];
    float* out = (float*)d_out;

    char* ws = (char*)d_ws;
    size_t off = 0;
    auto carve = [&](size_t bytes) -> char* {
        char* p = ws + off;
        off += (bytes + 255) & ~(size_t)255;
        return p;
    };
    _Float16* xb2 = (_Float16*)carve(67108864);
    _Float16* xb3 = (_Float16*)carve(33554432);
    _Float16* xb4 = (_Float16*)carve(16777216);
    _Float16* V2 = (_Float16*)carve(1572864);
    _Float16* V3 = (_Float16*)carve(524288);
    _Float16* V4 = (_Float16*)carve(1048576);
    float* V4d = (float*)carve(131072);
    _Float16* Wg = (_Float16*)carve(8388608);
    float* Sml = (float*)carve(262144);
    float* F3 = (float*)carve(1048576);
    float* F4d = (float*)carve(131072);
    if (ws_size < off) return;  // workspace too small: fail visibly, no OOB

    // post-flash buffers alias the (then-dead) xb2 region (26.5 MB < 64 MB)
    char* al = (char*)xb2;
    auto sub = [&](size_t bytes) -> char* {
        char* p = al;
        al += (bytes + 255) & ~(size_t)255;
        return p;
    };
    float* F2 = (float*)sub(3145728);
    _Float16* w4f = (_Float16*)sub(2097152);
    _Float16* w3f = (_Float16*)sub(9437184);
    _Float16* w2af = (_Float16*)sub(4718592);
    _Float16* w2bf = (_Float16*)sub(4718592);
    _Float16* G = (_Float16*)sub(1327104);
    _Float16* XB3 = (_Float16*)sub(294912);
    _Float16* XB4 = (_Float16*)sub(131072);
    float* V2m = (float*)sub(294912);
    _Float16* XB2 = (_Float16*)sub(147456);
    float* raw2 = (float*)sub(32768);
    float* raw3 = (float*)sub(32768);
    float* raw4 = (float*)sub(65536);

    repack_kernel<<<14336, 256, 0, stream>>>(c2, c3, c4, xb2, xb3, xb4);
    func_c2_kernel<<<2048, 256, 0, stream>>>(c2, V2);
    func_c3_kernel<<<4096, 256, 0, stream>>>(c3, V3);
    func_c4_kernel<<<8192, 256, 0, stream>>>(c4, V4, V4d);
    flash_kernel<<<256, 256, 0, stream>>>(xb2, xb3, xb4, V3, V4, Wg, Sml,
                                          F3, F4d, g3, g4);
    repack_w_kernel<<<2560, 256, 0, stream>>>(w4, w3, w2a, w2b, w4f, w3f, w2af, w2bf);
    proj_c2_kernel<<<64, 256, 0, stream>>>(Wg, Sml, V2, g2, F2);
    gather1_kernel<<<428, 256, 0, stream>>>(F2, F3, V4d, F4d, G, XB3, XB4);
    ep_gemm1_kernel<<<24, 256, 0, stream>>>(w2af, G, w3f, XB3, w4f, XB4,
                                            V2m, raw3, raw4);
    gather2_kernel<<<36, 256, 0, stream>>>(V2m, XB2);
    ep_gemm2_kernel<<<8, 256, 0, stream>>>(w2bf, XB2, raw2);
    final_kernel<<<16, 256, 0, stream>>>(raw2, raw3, raw4, V4d, b4, b2b,
                                         fcw, fcb, out);
}

// Round 5
// 732.150 us; speedup vs baseline: 2.5969x; 1.3572x over previous
//
#include <hip/hip_runtime.h>

typedef _Float16 h8 __attribute__((ext_vector_type(8)));
typedef float f4 __attribute__((ext_vector_type(4)));

#define DEVINL __device__ __forceinline__

// ---------------------------------------------------------------------------
// frag layout (mfma_f32_16x16x32_f16): element (row r, k):
//   frag = (r>>4)*(K>>5) + (k>>5); lane = ((k>>3)&3)*16 + (r&15); idx = k&7.
// One frag = 512 halves = 1 KB = one wave-wide dwordx4.
// ---------------------------------------------------------------------------

DEVINL void gload_lds(const _Float16* g, _Float16* l)
{
    __builtin_amdgcn_global_load_lds(
        (const __attribute__((address_space(1))) void*)g,
        (__attribute__((address_space(3))) void*)l, 16, 0, 0);
}

// ---------------------------------------------------------------------------
// Stage 1: functional kernels (verified rounds 1-3).
// ---------------------------------------------------------------------------

DEVINL void vtb_write(_Float16* vtb, int CB, int p, int d, float v)
{
    size_t off = (((size_t)(p >> 4) * CB) + (d >> 5)) * 512
               + (size_t)(((d >> 3) & 3) * 16 + (p & 15)) * 8 + (d & 7);
    vtb[off] = (_Float16)v;
}

extern "C" __global__ __launch_bounds__(256)
void func_c4_kernel(const float* __restrict__ x, _Float16* __restrict__ vtb,
                    float* __restrict__ V4d)
{
    int wave = threadIdx.x >> 6, lane = threadIdx.x & 63;
    int idx = blockIdx.x * 4 + wave;
    int b = idx >> 11, i = idx & 2047;
    size_t base = (size_t)(b * 2048 + i) * 256;
    float acc = 0.f;
#pragma unroll
    for (int it = 0; it < 4; ++it) acc += x[base + it * 64 + lane];
#pragma unroll
    for (int m = 1; m < 64; m <<= 1) acc += __shfl_xor(acc, m);
    float mean = acc * (1.f / 256.f);
    _Float16* vb = vtb + (size_t)b * 16 * 2048;
    if (lane < 16) vtb_write(vb, 64, lane, i, (lane == 0) ? mean : 0.f);
    if (lane == 0) V4d[b * 2048 + i] = mean;
}

extern "C" __global__ __launch_bounds__(256)
void func_c3_kernel(const float* __restrict__ x, _Float16* __restrict__ vtb)
{
    __shared__ float scr[4][12];
    int wave = threadIdx.x >> 6, lane = threadIdx.x & 63;
    int idx = blockIdx.x * 4 + wave;
    int b = idx >> 10, i = idx & 1023;
    size_t base = (size_t)(b * 1024 + i) * 1024;
    float acc = 0.f;
    for (int it = 0; it < 15; ++it) acc += x[base + it * 64 + lane];
    float vl = x[base + 15 * 64 + lane];
    acc += vl;
    float tr = (lane >= 32) ? vl : 0.f;
    float tcpre = acc;
    float xpre = tr;
#pragma unroll
    for (int m = 2; m < 32; m <<= 1) {
        acc += __shfl_xor(acc, m);
        tr += __shfl_xor(tr, m);
    }
    if ((lane & 31) < 2) {
        int rp = lane >> 5, cp = lane & 1;
        scr[wave][rp * 2 + cp] = acc;
        if (rp == 1) scr[wave][4 + cp] = tr;
    }
    if ((lane & 31) == 31) {
        int rp = lane >> 5;
        scr[wave][6 + rp] = tcpre;
        if (rp == 1) scr[wave][8] = xpre;
    }
    __syncthreads();
    if (lane < 16) {
        float out = 0.f;
        if (lane < 9) {
            int kh = lane / 3, kw = lane - kh * 3;
            int rp = (kh == 1) ? 0 : 1, cp = (kw == 1) ? 0 : 1;
            bool er = (kh == 0), ec = (kw == 0);
            const float* s = scr[wave];
            out = s[rp * 2 + cp];
            if (er) out -= s[4 + cp];
            if (ec) out -= s[6 + rp];
            if (er && ec) out += s[8];
        }
        vtb_write(vtb + (size_t)b * 16 * 1024, 32, lane, i, out);
    }
}

DEVINL float camU(const float* s, int p)
{
    int rc = p / 9, cc = p - rc * 9;
    int kh = rc / 3, kh2 = rc - kh * 3;
    int kw = cc / 3, kw2 = cc - kw * 3;
    int rm = (kh == 1) ? ((kh2 + 3) & 3) : (kh2 + 1);
    int cm = (kw == 1) ? ((kw2 + 3) & 3) : (kw2 + 1);
    bool er = (rc < 4), ec = (cc < 4);
    float u = s[rm * 4 + cm];
    if (er) u -= s[16 + (rm - 1) * 4 + cm];
    if (ec) u -= s[28 + rm * 3 + (cm - 1)];
    if (er && ec) u += s[40 + (rm - 1) * 3 + (cm - 1)];
    return u;
}

extern "C" __global__ __launch_bounds__(256)
void func_c2_kernel(const float* __restrict__ x, _Float16* __restrict__ vtb)
{
    __shared__ float scr[4][52];
    int wave = threadIdx.x >> 6, lane = threadIdx.x & 63;
    int idx = blockIdx.x * 4 + wave;
    int b = idx >> 9, i = idx & 511;
    size_t base = (size_t)(b * 512 + i) * 4096;
    float acc[4] = {0.f, 0.f, 0.f, 0.f};
    float tr[3];
    for (int it = 0; it < 60; it += 4) {
#pragma unroll
        for (int rr = 0; rr < 4; ++rr)
            acc[rr] += x[base + (size_t)(it + rr) * 64 + lane];
    }
    acc[0] += x[base + 60 * 64 + lane];
#pragma unroll
    for (int rr = 1; rr < 4; ++rr) {
        float v = x[base + (size_t)(60 + rr) * 64 + lane];
        acc[rr] += v;
        tr[rr - 1] = v;
    }
    float tcx[4], xr[3];
#pragma unroll
    for (int g = 0; g < 4; ++g) tcx[g] = acc[g];
#pragma unroll
    for (int g = 0; g < 3; ++g) xr[g] = tr[g];
#pragma unroll
    for (int m = 4; m < 64; m <<= 1) {
#pragma unroll
        for (int g = 0; g < 4; ++g) acc[g] += __shfl_xor(acc[g], m);
#pragma unroll
        for (int g = 0; g < 3; ++g) tr[g] += __shfl_xor(tr[g], m);
    }
    if (lane < 4) {
#pragma unroll
        for (int rm = 0; rm < 4; ++rm) scr[wave][rm * 4 + lane] = acc[rm];
#pragma unroll
        for (int rx = 0; rx < 3; ++rx) scr[wave][16 + rx * 4 + lane] = tr[rx];
    }
    if (lane >= 61) {
        int cx = lane - 61;
#pragma unroll
        for (int rm = 0; rm < 4; ++rm) scr[wave][28 + rm * 3 + cx] = tcx[rm];
#pragma unroll
        for (int rx = 0; rx < 3; ++rx) scr[wave][40 + rx * 3 + cx] = xr[rx];
    }
    __syncthreads();
    const float* s = scr[wave];
    _Float16* vb = vtb + (size_t)b * 96 * 512;
    vtb_write(vb, 16, lane, i, camU(s, lane));
    if (lane < 32) {
        int p = 64 + lane;
        vtb_write(vb, 16, p, i, (p < 81) ? camU(s, p) : 0.f);
    }
}

// ---------------------------------------------------------------------------
// Stage 2: repack fp32 row-major -> frag fp16 (generic 16 rows x 256 cols).
// ---------------------------------------------------------------------------
DEVINL void repack_tile(const float* __restrict__ src, _Float16* __restrict__ dst,
                        int K, int grp, int chunk, _Float16 (*T)[264])
{
    int tid = threadIdx.x;
    {
        int row = tid >> 4, t16 = tid & 15;
        const float* s = src + ((size_t)grp * 16 + row) * K + chunk * 256 + t16 * 16;
        float4 a = *(const float4*)(s + 0);
        float4 b = *(const float4*)(s + 4);
        float4 c = *(const float4*)(s + 8);
        float4 d = *(const float4*)(s + 12);
        h8 lo = {(_Float16)a.x, (_Float16)a.y, (_Float16)a.z, (_Float16)a.w,
                 (_Float16)b.x, (_Float16)b.y, (_Float16)b.z, (_Float16)b.w};
        h8 hi = {(_Float16)c.x, (_Float16)c.y, (_Float16)c.z, (_Float16)c.w,
                 (_Float16)d.x, (_Float16)d.y, (_Float16)d.z, (_Float16)d.w};
        *(h8*)&T[row][t16 * 16] = lo;
        *(h8*)&T[row][t16 * 16 + 8] = hi;
    }
    __syncthreads();
    int fl = tid >> 5, idx2 = tid & 31;
    size_t base = (size_t)grp * 16 * K + (size_t)(chunk * 8 + fl) * 512;
#pragma unroll
    for (int rep = 0; rep < 2; ++rep) {
        int idx = idx2 + rep * 32;
        int l16 = idx & 15, quad = idx >> 4;
        h8 v = *(h8*)&T[l16][fl * 32 + quad * 8];
        *(h8*)&dst[base + (size_t)idx * 8] = v;
    }
}

extern "C" __global__ __launch_bounds__(256)
void repack_kernel(const float* __restrict__ c2, const float* __restrict__ c3,
                   const float* __restrict__ c4, _Float16* __restrict__ xb2,
                   _Float16* __restrict__ xb3, _Float16* __restrict__ xb4)
{
    __shared__ _Float16 T[16][264];
    int bid = blockIdx.x;
    const float* src; _Float16* dst; int K, grp, chunk;
    if (bid < 8192) { src = c2; dst = xb2; K = 4096; grp = bid >> 4; chunk = bid & 15; }
    else if (bid < 12288) { int id = bid - 8192; src = c3; dst = xb3; K = 1024; grp = id >> 2; chunk = id & 3; }
    else { src = c4; dst = xb4; K = 256; grp = bid - 12288; chunk = 0; }
    repack_tile(src, dst, K, grp, chunk, T);
}

extern "C" __global__ __launch_bounds__(256)
void repack_w_kernel(const float* __restrict__ w4, const float* __restrict__ w3,
                     const float* __restrict__ w2a, const float* __restrict__ w2b,
                     _Float16* __restrict__ w4f, _Float16* __restrict__ w3f,
                     _Float16* __restrict__ w2af, _Float16* __restrict__ w2bf)
{
    __shared__ _Float16 T[16][264];
    int bid = blockIdx.x;
    const float* src; _Float16* dst; int K, grp, chunk;
    if (bid < 256) { src = w4; dst = w4f; K = 2048; grp = bid >> 3; chunk = bid & 7; }
    else if (bid < 1408) { int t = bid - 256; src = w3; dst = w3f; K = 9216; grp = t / 36; chunk = t - 36 * (t / 36); }
    else if (bid < 1984) { int t = bid - 1408; src = w2a; dst = w2af; K = 4608; grp = t / 18; chunk = t - 18 * (t / 18); }
    else { int t = bid - 1984; src = w2b; dst = w2bf; K = 4608; grp = t / 18; chunk = t - 18 * (t / 18); }
    repack_tile(src, dst, K, grp, chunk, T);
}

// ---------------------------------------------------------------------------
// Stage 3: fused CAM flash. 4 waves x 64 rows = 256-row blocks, 128-col d-tiles.
// ---------------------------------------------------------------------------
template <int N, int C, int DT, int MODE>
DEVINL void flash4(const _Float16* __restrict__ xfb, const _Float16* __restrict__ vtb,
                   float* __restrict__ Fout, float* __restrict__ FoutD,
                   _Float16* __restrict__ Wg, float* __restrict__ Sml,
                   const float* __restrict__ gptr, int r0, int c0,
                   _Float16* SB, _Float16* SWw)
{
    constexpr int KB = N >> 5;
    const int lane = threadIdx.x & 63;
    const int wave = threadIdx.x >> 6;
    const int l16 = lane & 15, quad = lane >> 4;
    const f4 fz = {0.f, 0.f, 0.f, 0.f};
    const size_t loff = (size_t)lane * 8;

    const _Float16* Abase = xfb + (size_t)((r0 >> 4) + wave * 4) * KB * 512 + loff;

    f4 accp[4];
    float m_run[4][4], l_run[4][4];
#pragma unroll
    for (int rt = 0; rt < 4; ++rt) {
        accp[rt] = fz;
#pragma unroll
        for (int g = 0; g < 4; ++g) { m_run[rt][g] = -3.0e38f; l_run[rt][g] = 0.f; }
    }

    h8 acur[4], anxt[4];
#pragma unroll
    for (int rt = 0; rt < 4; ++rt)
        acur[rt] = *(const h8*)(Abase + (size_t)rt * KB * 512);
    {
        int fr = wave * 2;
#pragma unroll
        for (int u = 0; u < 2; ++u)
            gload_lds(xfb + (size_t)(((c0 >> 4) + fr + u) * KB) * 512 + loff,
                      SB + ((size_t)(fr + u) << 9));
    }

    for (int dt = 0; dt < DT; ++dt) {
        const int d0 = c0 + dt * 128;
        f4 e[4][8];
#pragma unroll
        for (int rt = 0; rt < 4; ++rt)
#pragma unroll
            for (int ct = 0; ct < 8; ++ct) e[rt][ct] = fz;

#pragma unroll 2
        for (int kc = 0; kc < KB; ++kc) {
            const int buf = kc & 1;
            __syncthreads();
            if (!((dt == DT - 1) && (kc == KB - 1))) {
                int nkb = (kc == KB - 1) ? 0 : kc + 1;
                int nd0 = (kc == KB - 1) ? d0 + 128 : d0;
                int fr = wave * 2;
#pragma unroll
                for (int u = 0; u < 2; ++u)
                    gload_lds(xfb + (size_t)(((nd0 >> 4) + fr + u) * KB + nkb) * 512 + loff,
                              SB + ((size_t)((buf ^ 1) * 8 + fr + u) << 9));
#pragma unroll
                for (int rt = 0; rt < 4; ++rt)
                    anxt[rt] = *(const h8*)(Abase + ((size_t)rt * KB + nkb) * 512);
            }
#pragma unroll
            for (int ct = 0; ct < 8; ++ct) {
                h8 bf = *(const h8*)&SB[((size_t)(buf * 8 + ct) << 9) + loff];
#pragma unroll
                for (int rt = 0; rt < 4; ++rt)
                    e[rt][ct] = __builtin_amdgcn_mfma_f32_16x16x32_f16(acur[rt], bf, e[rt][ct], 0, 0, 0);
            }
#pragma unroll
            for (int rt = 0; rt < 4; ++rt) acur[rt] = anxt[rt];
        }

        // per-tile softmax (s = -energy)
#pragma unroll
        for (int rt = 0; rt < 4; ++rt) {
            float mx[4];
#pragma unroll
            for (int g = 0; g < 4; ++g) {
                float v = -e[rt][0][g];
#pragma unroll
                for (int ct = 1; ct < 8; ++ct) v = fmaxf(v, -e[rt][ct][g]);
                mx[g] = v;
            }
#pragma unroll
            for (int m = 1; m < 16; m <<= 1)
#pragma unroll
                for (int g = 0; g < 4; ++g) mx[g] = fmaxf(mx[g], __shfl_xor(mx[g], m));
            float mref[4], al[4];
            if (MODE != 3) {
#pragma unroll
                for (int g = 0; g < 4; ++g) {
                    float nm = fmaxf(m_run[rt][g], mx[g]);
                    al[g] = __expf(m_run[rt][g] - nm);
                    m_run[rt][g] = nm;
                    mref[g] = nm;
                    accp[rt][g] *= al[g];
                }
            } else {
#pragma unroll
                for (int g = 0; g < 4; ++g) mref[g] = mx[g];
            }
            float rs[4] = {0.f, 0.f, 0.f, 0.f};
#pragma unroll
            for (int ct = 0; ct < 8; ++ct) {
#pragma unroll
                for (int g = 0; g < 4; ++g) {
                    float w = __expf(-e[rt][ct][g] - mref[g]);
                    rs[g] += w;
                    int lane2 = ((ct * 2 + (l16 >> 3)) & 3) * 16 + quad * 4 + g;
                    SWw[((ct >> 1) << 9) + lane2 * 8 + (l16 & 7)] = (_Float16)w;
                }
            }
#pragma unroll
            for (int kc2 = 0; kc2 < 4; ++kc2) {
                h8 wa = *(const h8*)&SWw[((size_t)kc2 << 9) + loff];
                if (MODE == 3) {
                    int tile = (c0 >> 7) + dt;
                    int rfrag = (r0 >> 4) + wave * 4 + rt;
                    *(h8*)&Wg[((size_t)((tile * 32 + rfrag) * 4 + kc2) << 9) + loff] = wa;
                } else {
                    h8 vb = *(const h8*)(vtb + (((size_t)(d0 >> 5) + kc2) << 9) + loff);
                    accp[rt] = __builtin_amdgcn_mfma_f32_16x16x32_f16(wa, vb, accp[rt], 0, 0, 0);
                }
            }
#pragma unroll
            for (int m = 1; m < 16; m <<= 1)
#pragma unroll
                for (int g = 0; g < 4; ++g) rs[g] += __shfl_xor(rs[g], m);
            if (MODE == 3) {
                if (l16 == 0) {
                    int tile = (c0 >> 7) + dt;
#pragma unroll
                    for (int g = 0; g < 4; ++g) {
                        int row = r0 + wave * 64 + rt * 16 + quad * 4 + g;
                        Sml[((size_t)tile * 512 + row) * 2 + 0] = mref[g];
                        Sml[((size_t)tile * 512 + row) * 2 + 1] = rs[g];
                    }
                }
            } else {
#pragma unroll
                for (int g = 0; g < 4; ++g)
                    l_run[rt][g] = l_run[rt][g] * al[g] + rs[g];
            }
        }
    }
    if (MODE == 1) {
        float gam = gptr[0];
#pragma unroll
        for (int rt = 0; rt < 4; ++rt)
#pragma unroll
            for (int g = 0; g < 4; ++g) {
                int row = r0 + wave * 64 + rt * 16 + quad * 4 + g;
                float ident = (float)vtb[(size_t)(row >> 5) * 512
                               + (size_t)(((row >> 3) & 3) * 16 + l16) * 8 + (row & 7)];
                Fout[(size_t)row * 16 + l16] = gam * (accp[rt][g] / l_run[rt][g]) + ident;
            }
    } else if (MODE == 2) {
        float gam = gptr[0];
        if (l16 == 0) {
#pragma unroll
            for (int rt = 0; rt < 4; ++rt)
#pragma unroll
                for (int g = 0; g < 4; ++g) {
                    int row = r0 + wave * 64 + rt * 16 + quad * 4 + g;
                    float ident = (float)vtb[(size_t)(row >> 5) * 512
                                   + (size_t)(((row >> 3) & 3) * 16) * 8 + (row & 7)];
                    FoutD[row] = gam * (accp[rt][g] / l_run[rt][g]) + ident;
                }
        }
    }
}

extern "C" __global__ __launch_bounds__(256, 2)
void flash_kernel(const _Float16* __restrict__ xb2, const _Float16* __restrict__ xb3,
                  const _Float16* __restrict__ xb4,
                  const _Float16* __restrict__ V3, const _Float16* __restrict__ V4,
                  _Float16* __restrict__ Wg, float* __restrict__ Sml,
                  float* __restrict__ F3, float* __restrict__ F4d,
                  const float* __restrict__ g3, const float* __restrict__ g4)
{
    __shared__ _Float16 SB[16 * 512];
    __shared__ _Float16 SW[4 * 4 * 512];
    _Float16* SWw = &SW[(threadIdx.x >> 6) * 4 * 512];
    int bid = blockIdx.x;
    if (bid < 64) {                         // c2: MODE 3, 2x2 (row, d) split
        int xcd = bid & 7, s = bid >> 3;
        int b = xcd + 8 * (s & 1), unit = s >> 1;
        int rb = unit & 1, ds = unit >> 1;
        flash4<4096, 512, 2, 3>(xb2 + (size_t)b * 512 * 4096, nullptr, nullptr, nullptr,
                                Wg + (size_t)b * 262144, Sml + (size_t)b * 4096, nullptr,
                                rb * 256, ds * 256, SB, SWw);
    } else if (bid < 128) {                 // c3: MODE 1
        int t = bid - 64, xcd = t & 7, s = t >> 3;
        int b = xcd + 8 * (s & 1), rb = s >> 1;
        flash4<1024, 1024, 8, 1>(xb3 + (size_t)b * 1024 * 1024, V3 + (size_t)b * 16 * 1024,
                                 F3 + (size_t)b * 1024 * 16, nullptr, nullptr, nullptr, g3,
                                 rb * 256, 0, SB, SWw);
    } else {                                // c4: MODE 2
        int t = bid - 128, xcd = t & 7, s = t >> 3;
        int b = xcd + 8 * (s & 1), rb = s >> 1;
        flash4<256, 2048, 16, 2>(xb4 + (size_t)b * 2048 * 256, V4 + (size_t)b * 16 * 2048,
                                 nullptr, F4d + (size_t)b * 2048, nullptr, nullptr, g4,
                                 rb * 256, 0, SB, SWw);
    }
}

// ---------------------------------------------------------------------------
// Stage 4: c2 deferred projection: F2 = g2*(softmax@V2)+V2 from Wg + stats.
// ---------------------------------------------------------------------------
extern "C" __global__ __launch_bounds__(256)
void proj_c2_kernel(const _Float16* __restrict__ Wg, const float* __restrict__ Sml,
                    const _Float16* __restrict__ V2, const float* __restrict__ g2,
                    float* __restrict__ F2)
{
    int b = blockIdx.x >> 2, rb = blockIdx.x & 3;
    int lane = threadIdx.x & 63, wave = threadIdx.x >> 6;
    int l16 = lane & 15, quad = lane >> 4;
    size_t loff = (size_t)lane * 8;
    const _Float16* Wb = Wg + (size_t)b * 262144;
    const float* Sb = Sml + (size_t)b * 4096;
    const _Float16* Vb = V2 + (size_t)b * 96 * 512;
    const f4 fz = {0.f, 0.f, 0.f, 0.f};
    f4 accP[2][6];
    float M[2][4], L[2][4];
#pragma unroll
    for (int rt = 0; rt < 2; ++rt) {
#pragma unroll
        for (int pt = 0; pt < 6; ++pt) accP[rt][pt] = fz;
#pragma unroll
        for (int g = 0; g < 4; ++g) { M[rt][g] = -3.0e38f; L[rt][g] = 0.f; }
    }
    for (int t = 0; t < 4; ++t) {
        f4 tmp[2][6];
#pragma unroll
        for (int rt = 0; rt < 2; ++rt)
#pragma unroll
            for (int pt = 0; pt < 6; ++pt) tmp[rt][pt] = fz;
#pragma unroll
        for (int kb = 0; kb < 4; ++kb) {
            h8 wa[2];
#pragma unroll
            for (int rt = 0; rt < 2; ++rt) {
                int rfrag = rb * 8 + wave * 2 + rt;
                wa[rt] = *(const h8*)&Wb[((size_t)((t * 32 + rfrag) * 4 + kb) << 9) + loff];
            }
#pragma unroll
            for (int pt = 0; pt < 6; ++pt) {
                h8 vb = *(const h8*)&Vb[((size_t)(pt * 16 + t * 4 + kb) << 9) + loff];
#pragma unroll
                for (int rt = 0; rt < 2; ++rt)
                    tmp[rt][pt] = __builtin_amdgcn_mfma_f32_16x16x32_f16(wa[rt], vb, tmp[rt][pt], 0, 0, 0);
            }
        }
#pragma unroll
        for (int rt = 0; rt < 2; ++rt)
#pragma unroll
            for (int g = 0; g < 4; ++g) {
                int row = (rb * 8 + wave * 2 + rt) * 16 + quad * 4 + g;
                float mt = Sb[((size_t)t * 512 + row) * 2 + 0];
                float lt = Sb[((size_t)t * 512 + row) * 2 + 1];
                float nm = fmaxf(M[rt][g], mt);
                float ao = __expf(M[rt][g] - nm);
                float at = __expf(mt - nm);
#pragma unroll
                for (int pt = 0; pt < 6; ++pt)
                    accP[rt][pt][g] = accP[rt][pt][g] * ao + at * tmp[rt][pt][g];
                L[rt][g] = L[rt][g] * ao + at * lt;
                M[rt][g] = nm;
            }
    }
    float gam = g2[0];
#pragma unroll
    for (int rt = 0; rt < 2; ++rt)
#pragma unroll
        for (int pt = 0; pt < 6; ++pt)
#pragma unroll
            for (int g = 0; g < 4; ++g) {
                int row = (rb * 8 + wave * 2 + rt) * 16 + quad * 4 + g;
                int p = pt * 16 + l16;
                float ident = (float)Vb[((size_t)pt * 16 + (row >> 5)) * 512
                               + (size_t)(((row >> 3) & 3) * 16 + (p & 15)) * 8 + (row & 7)];
                F2[((size_t)b * 512 + row) * 96 + p] = gam * (accP[rt][pt][g] / L[rt][g]) + ident;
            }
}

// ---------------------------------------------------------------------------
// Stage 5: gather activations into B-frag fp16 tensors for epilogue GEMMs.
// ---------------------------------------------------------------------------
extern "C" __global__ __launch_bounds__(256)
void gather1_kernel(const float* __restrict__ F2, const float* __restrict__ F3,
                    const float* __restrict__ V4d, const float* __restrict__ F4d,
                    _Float16* __restrict__ G, _Float16* __restrict__ XB3,
                    _Float16* __restrict__ XB4)
{
    int gid = blockIdx.x * 256 + threadIdx.x;
    int lane = gid & 63, fragid = gid >> 6;
    int kq = lane >> 4, n16 = lane & 15;
    _Float16 v[8];
    if (fragid < 1296) {                    // G[(i,k2)][(b,kcol)]
        int nb = fragid / 144, kb = fragid - nb * 144;
        int n = nb * 16 + n16;
        int b = n / 9, kcol = n - b * 9;
        int kh = kcol / 3, kw = kcol - kh * 3;
#pragma unroll
        for (int j = 0; j < 8; ++j) {
            int K = kb * 32 + kq * 8 + j;
            int i = K / 9, k2 = K - i * 9;
            int kh2 = k2 / 3, kw2 = k2 - kh2 * 3;
            int p = (kh * 3 + kh2) * 9 + kw * 3 + kw2;
            v[j] = (_Float16)F2[((size_t)b * 512 + i) * 96 + p];
        }
        *(h8*)&G[((size_t)fragid << 9) + lane * 8] = *(h8*)v;
    } else if (fragid < 1584) {             // XB3[(i,k)][b]
        int kb = fragid - 1296;
#pragma unroll
        for (int j = 0; j < 8; ++j) {
            int K = kb * 32 + kq * 8 + j;
            int i = K / 9, k9 = K - i * 9;
            v[j] = (_Float16)F3[((size_t)n16 * 1024 + i) * 16 + k9];
        }
        *(h8*)&XB3[((size_t)kb << 9) + lane * 8] = *(h8*)v;
    } else {                                // XB4[i][(b,which)]
        int f = fragid - 1584;
        int nb = f >> 6, kb = f & 63;
        const float* src = nb ? F4d : V4d;
#pragma unroll
        for (int j = 0; j < 8; ++j) {
            int i = kb * 32 + kq * 8 + j;
            v[j] = (_Float16)src[(size_t)n16 * 2048 + i];
        }
        *(h8*)&XB4[((size_t)f << 9) + lane * 8] = *(h8*)v;
    }
}

// gather XB2 from V2m split partials (fused 9-way reduce)
extern "C" __global__ __launch_bounds__(256)
void gather2_kernel(const float* __restrict__ Pv, _Float16* __restrict__ XB2)
{
    int gid = blockIdx.x * 256 + threadIdx.x;   // 144 frags x 64 lanes
    int lane = gid & 63, kb = gid >> 6;
    int kq = lane >> 4, b = lane & 15;
    _Float16 v[8];
#pragma unroll
    for (int j = 0; j < 8; ++j) {
        int K = kb * 32 + kq * 8 + j;
        int jj = K / 9, k = K - jj * 9;
        float s = 0.f;
#pragma unroll
        for (int ss = 0; ss < 9; ++ss)
            s += Pv[((size_t)ss * 8192 + (size_t)b * 512 + jj) * 9 + k];
        v[j] = (_Float16)s;
    }
    *(h8*)&XB2[((size_t)kb << 9) + lane * 8] = *(h8*)v;
}

// ---------------------------------------------------------------------------
// Stage 6: epilogue GEMMs (MFMA), split-K for occupancy.
// ---------------------------------------------------------------------------
extern "C" __global__ __launch_bounds__(256)
void ep_gemm1_kernel(const _Float16* __restrict__ w2af, const _Float16* __restrict__ G,
                     const _Float16* __restrict__ w3f, const _Float16* __restrict__ XB3,
                     const _Float16* __restrict__ w4f, const _Float16* __restrict__ XB4,
                     float* __restrict__ Pv, float* __restrict__ Pr3,
                     float* __restrict__ Pr4)
{
    int lane = threadIdx.x & 63, wave = threadIdx.x >> 6;
    int l16 = lane & 15, quad = lane >> 4;
    size_t loff = (size_t)lane * 8;
    const f4 fz = {0.f, 0.f, 0.f, 0.f};
    int bid = blockIdx.x;
    if (bid < 72) {                         // V2m partials: 32 mt x 9 splits
        int unit = bid * 4 + wave;          // [0,288)
        int mt = unit & 31, s = unit >> 5;
        f4 acc[9];
#pragma unroll
        for (int nb = 0; nb < 9; ++nb) acc[nb] = fz;
#pragma unroll 2
        for (int kf = s * 16; kf < s * 16 + 16; ++kf) {
            h8 a = *(const h8*)&w2af[(((size_t)(mt * 144 + kf)) << 9) + loff];
#pragma unroll
            for (int nb = 0; nb < 9; ++nb) {
                h8 bfr = *(const h8*)&G[(((size_t)(nb * 144 + kf)) << 9) + loff];
                acc[nb] = __builtin_amdgcn_mfma_f32_16x16x32_f16(a, bfr, acc[nb], 0, 0, 0);
            }
        }
#pragma unroll
        for (int nb = 0; nb < 9; ++nb)
#pragma unroll
            for (int g = 0; g < 4; ++g) {
                int j = mt * 16 + quad * 4 + g;
                int n = nb * 16 + l16;
                int b = n / 9, k = n - b * 9;
                Pv[((size_t)s * 8192 + (size_t)b * 512 + j) * 9 + k] = acc[nb][g];
            }
    } else if (bid < 216) {                 // raw3 partials: 32 mt x 18 splits
        int unit = (bid - 72) * 4 + wave;   // [0,576)
        int mt = unit & 31, s = unit >> 5;
        f4 acc = fz;
#pragma unroll 4
        for (int kf = s * 16; kf < s * 16 + 16; ++kf) {
            h8 a = *(const h8*)&w3f[(((size_t)(mt * 288 + kf)) << 9) + loff];
            h8 bfr = *(const h8*)&XB3[((size_t)kf << 9) + loff];
            acc = __builtin_amdgcn_mfma_f32_16x16x32_f16(a, bfr, acc, 0, 0, 0);
        }
#pragma unroll
        for (int g = 0; g < 4; ++g)
            Pr3[(size_t)(s * 512 + mt * 16 + quad * 4 + g) * 16 + l16] = acc[g];
    } else {                                // raw4 partials: 32 mt x 8 splits
        int unit = (bid - 216) * 4 + wave;  // [0,256)
        int mt = unit & 31, s = unit >> 5;
        f4 acc[2] = {fz, fz};
#pragma unroll 2
        for (int kf = s * 8; kf < s * 8 + 8; ++kf) {
            h8 a = *(const h8*)&w4f[(((size_t)(mt * 64 + kf)) << 9) + loff];
#pragma unroll
            for (int nb = 0; nb < 2; ++nb) {
                h8 bfr = *(const h8*)&XB4[(((size_t)(nb * 64 + kf)) << 9) + loff];
                acc[nb] = __builtin_amdgcn_mfma_f32_16x16x32_f16(a, bfr, acc[nb], 0, 0, 0);
            }
        }
#pragma unroll
        for (int nb = 0; nb < 2; ++nb)
#pragma unroll
            for (int g = 0; g < 4; ++g)
                Pr4[((size_t)s * 1024 + (size_t)nb * 512 + mt * 16 + quad * 4 + g) * 16 + l16] = acc[nb][g];
    }
}

extern "C" __global__ __launch_bounds__(256)
void ep_gemm2_kernel(const _Float16* __restrict__ w2bf, const _Float16* __restrict__ XB2,
                     float* __restrict__ Pr2)
{
    int lane = threadIdx.x & 63, wave = threadIdx.x >> 6;
    int l16 = lane & 15, quad = lane >> 4;
    size_t loff = (size_t)lane * 8;
    int unit = blockIdx.x * 4 + wave;       // [0,288): 32 mt x 9 splits
    int mt = unit & 31, s = unit >> 5;
    f4 acc = {0.f, 0.f, 0.f, 0.f};
#pragma unroll 4
    for (int kf = s * 16; kf < s * 16 + 16; ++kf) {
        h8 a = *(const h8*)&w2bf[(((size_t)(mt * 144 + kf)) << 9) + loff];
        h8 bfr = *(const h8*)&XB2[((size_t)kf << 9) + loff];
        acc = __builtin_amdgcn_mfma_f32_16x16x32_f16(a, bfr, acc, 0, 0, 0);
    }
#pragma unroll
    for (int g = 0; g < 4; ++g)
        Pr2[(size_t)(s * 512 + mt * 16 + quad * 4 + g) * 16 + l16] = acc[g];
}

// ---------------------------------------------------------------------------
// Stage 7: PF assembly (sums split partials) + FC, fused.
// ---------------------------------------------------------------------------
extern "C" __global__ __launch_bounds__(256)
void final_kernel(const float* __restrict__ Pr2, const float* __restrict__ Pr3,
                  const float* __restrict__ Pr4, const float* __restrict__ V4d,
                  const float* __restrict__ b4, const float* __restrict__ b2b,
                  const float* __restrict__ fcw, const float* __restrict__ fcb,
                  float* __restrict__ out)
{
    __shared__ float pf[3584];
    __shared__ float r0s[256], r1s[256];
    int b = blockIdx.x, tid = threadIdx.x;
    for (int o = tid; o < 512; o += 256) {
        float pd = 0.f, pa = 0.f;
#pragma unroll
        for (int s = 0; s < 8; ++s) {
            pd += Pr4[(size_t)(s * 1024 + o) * 16 + b];
            pa += Pr4[(size_t)(s * 1024 + 512 + o) * 16 + b];
        }
        float r3 = 0.f;
#pragma unroll
        for (int s = 0; s < 18; ++s) r3 += Pr3[(size_t)(s * 512 + o) * 16 + b];
        float r2 = 0.f;
#pragma unroll
        for (int s = 0; s < 9; ++s) r2 += Pr2[(size_t)(s * 512 + o) * 16 + b];
        float pd4 = pd + b4[o];
        pf[1024 + o] = pa + b4[o] + pd4;
        pf[512 + o] = r3 * (1.f / 256.f) + pd4;
        pf[o] = r2 * (1.f / 256.f) + b2b[o] + pd4;
    }
    for (int i = tid; i < 2048; i += 256) pf[1536 + i] = V4d[(size_t)b * 2048 + i];
    __syncthreads();
    float p0 = 0.f, p1 = 0.f;
    for (int k = tid; k < 3584; k += 256) {
        float f = pf[k];
        p0 += fcw[k] * f;
        p1 += fcw[3584 + k] * f;
    }
    r0s[tid] = p0;
    r1s[tid] = p1;
    __syncthreads();
    for (int s = 128; s > 0; s >>= 1) {
        if (tid < s) { r0s[tid] += r0s[tid + s]; r1s[tid] += r1s[tid + s]; }
        __syncthreads();
    }
    if (tid == 0) {
        out[b * 2 + 0] = r0s[0] + fcb[0];
        out[b * 2 + 1] = r1s[0] + fcb[1];
    }
}

// ---------------------------------------------------------------------------

extern "C" void kernel_launch(void* const* d_in, const int* in_sizes, int n_in,
                              void* d_out, int out_size, void* d_ws, size_t ws_size,
                              hipStream_t stream)
{
    const float* c2 = (const float*)d_in[0];
    const float* c3 = (const float*)d_in[1];
    const float* c4 = (const float*)d_in[2];
    const float* w4 = (const float*)d_in[3];
    const float* b4 = (const float*)d_in[4];
    const float* w3 = (const float*)d_in[5];
    const float* w2a = (const float*)d_in[6];
    const float* w2b = (const float*)d_in[7];
    const float* b2b = (const float*)d_in[8];
    const float* g2 = (const float*)d_in[9];
    const float* g3 = (const float*)d_in[10];
    const float* g4 = (const float*)d_in[11];
    const float* fcw = (const float*)d_in[12];
    const float* fcb = (const float*)d_in[13];
    float* out = (float*)d_out;

    char* ws = (char*)d_ws;
    size_t off = 0;
    auto carve = [&](size_t bytes) -> char* {
        char* p = ws + off;
        off += (bytes + 255) & ~(size_t)255;
        return p;
    };
    _Float16* xb2 = (_Float16*)carve(67108864);
    _Float16* xb3 = (_Float16*)carve(33554432);
    _Float16* xb4 = (_Float16*)carve(16777216);
    _Float16* V2 = (_Float16*)carve(1572864);
    _Float16* V3 = (_Float16*)carve(524288);
    _Float16* V4 = (_Float16*)carve(1048576);
    float* V4d = (float*)carve(131072);
    _Float16* Wg = (_Float16*)carve(8388608);
    float* Sml = (float*)carve(262144);
    float* F3 = (float*)carve(1048576);
    float* F4d = (float*)carve(131072);
    if (ws_size < off) return;  // workspace too small: fail visibly, no OOB

    // post-flash buffers alias the (then-dead) xb2 region (~31 MB < 64 MB)
    char* al = (char*)xb2;
    auto sub = [&](size_t bytes) -> char* {
        char* p = al;
        al += (bytes + 255) & ~(size_t)255;
        return p;
    };
    float* F2 = (float*)sub(3145728);
    _Float16* w4f = (_Float16*)sub(2097152);
    _Float16* w3f = (_Float16*)sub(9437184);
    _Float16* w2af = (_Float16*)sub(4718592);
    _Float16* w2bf = (_Float16*)sub(4718592);
    _Float16* G = (_Float16*)sub(1327104);
    _Float16* XB3 = (_Float16*)sub(294912);
    _Float16* XB4 = (_Float16*)sub(131072);
    float* Pv = (float*)sub(2654208);
    _Float16* XB2 = (_Float16*)sub(147456);
    float* Pr2 = (float*)sub(294912);
    float* Pr3 = (float*)sub(589824);
    float* Pr4 = (float*)sub(524288);

    repack_kernel<<<14336, 256, 0, stream>>>(c2, c3, c4, xb2, xb3, xb4);
    func_c2_kernel<<<2048, 256, 0, stream>>>(c2, V2);
    func_c3_kernel<<<4096, 256, 0, stream>>>(c3, V3);
    func_c4_kernel<<<8192, 256, 0, stream>>>(c4, V4, V4d);
    flash_kernel<<<256, 256, 0, stream>>>(xb2, xb3, xb4, V3, V4, Wg, Sml,
                                          F3, F4d, g3, g4);
    repack_w_kernel<<<2560, 256, 0, stream>>>(w4, w3, w2a, w2b, w4f, w3f, w2af, w2bf);
    proj_c2_kernel<<<64, 256, 0, stream>>>(Wg, Sml, V2, g2, F2);
    gather1_kernel<<<428, 256, 0, stream>>>(F2, F3, V4d, F4d, G, XB3, XB4);
    ep_gemm1_kernel<<<280, 256, 0, stream>>>(w2af, G, w3f, XB3, w4f, XB4,
                                             Pv, Pr3, Pr4);
    gather2_kernel<<<36, 256, 0, stream>>>(Pv, XB2);
    ep_gemm2_kernel<<<72, 256, 0, stream>>>(w2bf, XB2, Pr2);
    final_kernel<<<16, 256, 0, stream>>>(Pr2, Pr3, Pr4, V4d, b4, b2b,
                                         fcw, fcb, out);
}